// Round 2
// baseline (3890.627 us; speedup 1.0000x reference)
//
#include <hip/hip_runtime.h>
#include <hip/hip_cooperative_groups.h>

namespace cg = cooperative_groups;

// Micromagnetic LLG + RK4, 128x128 grid, 256 signal steps.
// Exact simplifications (verified R0, absmax ~2e-31):
//  - 100 relaxation steps are a bit-exact no-op (uniform m = y-hat =>
//    zero Laplacian, zero demag (mz=0), zero SOT (m == p)); m0 = y-hat, m0_z=0.
//  - probe value = mz_new * Msat.
//
// R1: single persistent cooperative kernel. 64 blocks x 256 threads own
// 16x16 tiles with halo-4 in LDS; all 4 RK4 substeps computed locally on
// shrinking regions (22->20->18->16). Static fields (B_ext, Msat-derived)
// staged in LDS ONCE. Per step: write interior to double-buffered global m,
// ONE grid.sync(), reload the 320-cell halo ring. Double buffering makes a
// single sync per step race-free (buf[t&1] is not rewritten until 2 syncs
// after its readers).

#define GNX 128
#define NPLANE (GNX*GNX)
#define T_STEPS 256

constexpr int TW   = 16;
constexpr int HALO = 4;
constexpr int EXT  = TW + 2*HALO;    // 24
constexpr int NBS  = GNX / TW;       // 8
constexpr int NBLK = NBS * NBS;      // 64
constexpr int NTHR = 256;
constexpr int RING = EXT*EXT - TW*TW;  // 320

constexpr float F_H    = (float)(175950000000.0 * 1e-13);            // GAMMA*DT
constexpr float F_H6   = (float)(175950000000.0 * 1e-13 / 6.0);
constexpr float F_IDX2 = (float)(1.0 / (5e-09 * 5e-09));
constexpr float F_2A   = (float)(2.0 * 1.3e-11);
constexpr float F_NMU0 = (float)(-(4e-07 * 3.14159265358979323846));
constexpr float F_CSOT = 0.001f;
constexpr float F_ALPHA= 0.02f;
constexpr float F_CLLG = (float)(-(1.0 / (1.0 + 0.02*0.02)));

struct V3 { float x, y, z; };

// cex = 2A/Msat (pre-divided), dmg = -MU0*Msat (pre-multiplied)
__device__ __forceinline__ V3 torque_llg(
    float mx, float my, float mz,
    float sux, float suy, float suz,
    float bx, float by, float bz, float cex, float dmg)
{
    const float lx = (sux - 4.0f*mx) * F_IDX2;
    const float ly = (suy - 4.0f*my) * F_IDX2;
    const float lz = (suz - 4.0f*mz) * F_IDX2;
    const float bex = bx + cex*lx;
    const float bey = by + cex*ly;
    const float bez = (bz + cex*lz) + dmg*mz;
    const float ax = my*bez - mz*bey;
    const float ay = mz*bex - mx*bez;
    const float az = mx*bey - my*bex;
    const float cx = my*az - mz*ay;
    const float cy = mz*ax - mx*az;
    const float cz = mx*ay - my*ax;
    // sot = C_SOT * (m x (m x p)), p=(0,1,0): q = m x p = (-mz, 0, mx)
    const float sx = my*mx;            // my*qz - mz*qy = my*mx
    const float sy = mz*(-mz) - mx*mx; // mz*qx - mx*qz
    const float sz = my*mz;            // mx*qy - my*qx = -my*(-mz)
    V3 t;
    t.x = F_CLLG*(ax + F_ALPHA*cx) + F_CSOT*sx;
    t.y = F_CLLG*(ay + F_ALPHA*cy) + F_CSOT*sy;
    t.z = F_CLLG*(az + F_ALPHA*cz) + F_CSOT*sz;
    return t;
}

__global__ __launch_bounds__(NTHR, 1) void mm_persist(
    const float* __restrict__ signal, const float* __restrict__ B_ext,
    const float* __restrict__ Msat, const int* __restrict__ src_idx,
    const int* __restrict__ probe_idx, float* __restrict__ out,
    float* __restrict__ ws)
{
    cg::grid_group grid = cg::this_grid();

    __shared__ float mb[3][EXT][EXT];   // m at step start (pristine)
    __shared__ float tb[3][EXT][EXT];   // trial field
    __shared__ float bxs[3][EXT][EXT];  // B_ext (time-invariant)
    __shared__ float mci[EXT][EXT];     // 2A/Msat
    __shared__ float mdg[EXT][EXT];     // -MU0*Msat
    __shared__ float ka[3][NTHR];       // RK4 accumulator

    const int tid = threadIdx.x;
    const int br = blockIdx.x / NBS, bc = blockIdx.x - (blockIdx.x/NBS)*NBS;
    const int r0 = br*TW, c0 = bc*TW;

    // ---- one-time staging: B_ext, Msat planes, analytic m init ----
    for (int i = tid; i < 3*EXT*EXT; i += NTHR) {
        const int comp = i / (EXT*EXT);
        const int rem  = i - comp*(EXT*EXT);
        const int er = rem / EXT, ec = rem - (rem/EXT)*EXT;
        const int gr = min(max(r0 - HALO + er, 0), GNX-1);
        const int gc = min(max(c0 - HALO + ec, 0), GNX-1);
        bxs[comp][er][ec] = B_ext[comp*NPLANE + gr*GNX + gc];
        mb[comp][er][ec]  = (comp == 1) ? 1.0f : 0.0f;   // m0 = y-hat
    }
    for (int i = tid; i < EXT*EXT; i += NTHR) {
        const int er = i / EXT, ec = i - (i/EXT)*EXT;
        const int gr = min(max(r0 - HALO + er, 0), GNX-1);
        const int gc = min(max(c0 - HALO + ec, 0), GNX-1);
        const float ms = Msat[gr*GNX + gc];
        mci[er][ec] = F_2A / ms;
        mdg[er][ec] = F_NMU0 * ms;
    }

    const int s0r = src_idx[0], s0c = src_idx[1];
    const int s1r = src_idx[2], s1c = src_idx[3];
    int pr[4], pc[4];
    #pragma unroll
    for (int j = 0; j < 4; ++j) { pr[j] = probe_idx[2*j]; pc[j] = probe_idx[2*j+1]; }

    const int ir_o = tid / TW, ic_o = tid - (tid/TW)*TW;
    const int gr_o = r0 + ir_o, gc_o = c0 + ic_o;
    const float msat_o = Msat[gr_o*GNX + gc_o];

    for (int t = 0; t < T_STEPS; ++t) {
        float* mcur = ws + (t & 1) * 3*NPLANE;
        const float sg0 = signal[2*t + 0];
        const float sg1 = signal[2*t + 1];
        ka[0][tid] = 0.0f; ka[1][tid] = 0.0f; ka[2][tid] = 0.0f;
        __syncthreads();   // staging/ring writes + ka zero visible

        // ---- 4 RK4 substeps on shrinking regions ----
        #pragma unroll
        for (int k = 0; k < 4; ++k) {
            const int W   = (k == 0) ? 22 : (k == 1) ? 20 : (k == 2) ? 18 : 16;
            const int off = (EXT - W) / 2;
            const float wk = (k == 1 || k == 2) ? 2.0f : 1.0f;
            const float cc = (k == 2) ? 1.0f : 0.5f;

            float trv[2][3];
            int   thas[2] = {0, 0};
            int   ter[2], tec[2];

            for (int ii = 0, i = tid; i < W*W; i += NTHR, ++ii) {
                const int er = off + i / W;
                const int ec = off + (i - (i/W)*W);
                const int gr = r0 - HALO + er, gc = c0 - HALO + ec;
                if (gr < 0 || gr >= GNX || gc < 0 || gc >= GNX) continue;

                const int eru = (gr == 0)      ? er : er - 1;
                const int erd = (gr == GNX-1)  ? er : er + 1;
                const int ecl = (gc == 0)      ? ec : ec - 1;
                const int ecr = (gc == GNX-1)  ? ec : ec + 1;

                float mx, my, mz, sux, suy, suz;
                if (k == 0) {
                    mx = mb[0][er][ec]; my = mb[1][er][ec]; mz = mb[2][er][ec];
                    sux = ((mb[0][erd][ec] + mb[0][eru][ec]) + mb[0][er][ecr]) + mb[0][er][ecl];
                    suy = ((mb[1][erd][ec] + mb[1][eru][ec]) + mb[1][er][ecr]) + mb[1][er][ecl];
                    suz = ((mb[2][erd][ec] + mb[2][eru][ec]) + mb[2][er][ecr]) + mb[2][er][ecl];
                } else {
                    mx = tb[0][er][ec]; my = tb[1][er][ec]; mz = tb[2][er][ec];
                    sux = ((tb[0][erd][ec] + tb[0][eru][ec]) + tb[0][er][ecr]) + tb[0][er][ecl];
                    suy = ((tb[1][erd][ec] + tb[1][eru][ec]) + tb[1][er][ecr]) + tb[1][er][ecl];
                    suz = ((tb[2][erd][ec] + tb[2][eru][ec]) + tb[2][er][ecr]) + tb[2][er][ecl];
                }

                float bx = bxs[0][er][ec];
                float by = bxs[1][er][ec];
                float bz = bxs[2][er][ec];
                if (gr == s0r && gc == s0c) bz = sg0;
                if (gr == s1r && gc == s1c) bz = sg1;

                const V3 tq = torque_llg(mx, my, mz, sux, suy, suz,
                                         bx, by, bz, mci[er][ec], mdg[er][ec]);

                const int ir = er - HALO, ic = ec - HALO;
                if (ir >= 0 && ir < TW && ic >= 0 && ic < TW) {
                    const int idx = ir*TW + ic;
                    ka[0][idx] += wk*tq.x;
                    ka[1][idx] += wk*tq.y;
                    ka[2][idx] += wk*tq.z;
                }
                if (k < 3) {
                    trv[ii][0] = mb[0][er][ec] + (F_H*tq.x)*cc;
                    trv[ii][1] = mb[1][er][ec] + (F_H*tq.y)*cc;
                    trv[ii][2] = mb[2][er][ec] + (F_H*tq.z)*cc;
                    thas[ii] = 1; ter[ii] = er; tec[ii] = ec;
                }
            }
            if (k < 3) {
                __syncthreads();
                #pragma unroll
                for (int ii = 0; ii < 2; ++ii) {
                    if (thas[ii]) {
                        tb[0][ter[ii]][tec[ii]] = trv[ii][0];
                        tb[1][ter[ii]][tec[ii]] = trv[ii][1];
                        tb[2][ter[ii]][tec[ii]] = trv[ii][2];
                    }
                }
                __syncthreads();
            }
        }
        __syncthreads();   // ka accumulation complete

        // ---- final update: own interior cell; refresh LDS + global ----
        {
            const int er = HALO + ir_o, ec = HALO + ic_o;
            const float nx = mb[0][er][ec] + F_H6 * ka[0][tid];
            const float ny = mb[1][er][ec] + F_H6 * ka[1][tid];
            const float nz = mb[2][er][ec] + F_H6 * ka[2][tid];
            mb[0][er][ec] = nx; mb[1][er][ec] = ny; mb[2][er][ec] = nz;
            mcur[0*NPLANE + gr_o*GNX + gc_o] = nx;
            mcur[1*NPLANE + gr_o*GNX + gc_o] = ny;
            mcur[2*NPLANE + gr_o*GNX + gc_o] = nz;
            #pragma unroll
            for (int j = 0; j < 4; ++j) {
                if (gr_o == pr[j] && gc_o == pc[j]) {
                    out[t*4 + j] = nz * msat_o;   // m0_z == 0 exactly
                }
            }
        }

        grid.sync();   // all interiors for step t globally visible

        // ---- reload halo ring from the just-written buffer ----
        for (int i = tid; i < 3*RING; i += NTHR) {
            const int comp = i / RING;
            const int r = i - comp*RING;
            int er, ec;
            if (r < 4*EXT) {                       // top 4 rows
                er = r / EXT; ec = r - (r/EXT)*EXT;
            } else if (r < 8*EXT) {                // bottom 4 rows
                const int q = r - 4*EXT;
                er = (EXT-4) + q / EXT; ec = q - (q/EXT)*EXT;
            } else {                               // side bands, rows 4..19
                const int q = r - 8*EXT;
                er = HALO + (q >> 3);
                const int c = q & 7;
                ec = (c < 4) ? c : (TW + c);
            }
            const int gr = min(max(r0 - HALO + er, 0), GNX-1);
            const int gc = min(max(c0 - HALO + ec, 0), GNX-1);
            mb[comp][er][ec] = mcur[comp*NPLANE + gr*GNX + gc];
        }
        // (next iteration's post-ka-zero __syncthreads orders these writes)
    }
}

extern "C" void kernel_launch(void* const* d_in, const int* in_sizes, int n_in,
                              void* d_out, int out_size, void* d_ws, size_t ws_size,
                              hipStream_t stream) {
    const float* sig  = (const float*)d_in[0];
    const float* Bex  = (const float*)d_in[1];
    const float* Ms   = (const float*)d_in[2];
    const int*   srci = (const int*)d_in[3];
    const int*   prbi = (const int*)d_in[4];
    float* out = (float*)d_out;
    float* ws  = (float*)d_ws;

    void* args[] = { (void*)&sig, (void*)&Bex, (void*)&Ms,
                     (void*)&srci, (void*)&prbi, (void*)&out, (void*)&ws };
    hipLaunchCooperativeKernel((const void*)mm_persist, dim3(NBLK), dim3(NTHR),
                               args, 0, stream);
}

// Round 3
// 3070.042 us; speedup vs baseline: 1.2673x; 1.2673x over previous
//
#include <hip/hip_runtime.h>

// Micromagnetic LLG + RK4, 128x128 grid, 256 signal steps.
// Exact simplifications (verified R0/R1, absmax ~2e-31):
//  - 100 relaxation steps are a bit-exact no-op => m0 = y-hat, m0_z = 0.
//  - probe value = mz_new * Msat.
//
// R2: persistent cooperative kernel WITHOUT grid.sync (R1 showed grid.sync
// costs ~13us/step on 8 XCDs). Point-to-point neighbor sync instead:
// per-block progress flags in ws; publish = __threadfence + release store
// (agent scope); wait = acquire spin on <=8 neighbors' flags. Double-buffered
// global m bounds neighbor skew to 1 step, making one wait per step
// race-free. ws 0xAA poison reads as negative int => spins safely without
// pre-zeroing.

#define GNX 128
#define NPLANE (GNX*GNX)
#define T_STEPS 256

constexpr int TW   = 16;
constexpr int HALO = 4;
constexpr int EXT  = TW + 2*HALO;    // 24
constexpr int NBS  = GNX / TW;       // 8
constexpr int NBLK = NBS * NBS;      // 64
constexpr int NTHR = 256;
constexpr int RING = EXT*EXT - TW*TW;  // 320
constexpr int FSTR = 32;             // flag stride in ints (128 B/line)

constexpr float F_H    = (float)(175950000000.0 * 1e-13);            // GAMMA*DT
constexpr float F_H6   = (float)(175950000000.0 * 1e-13 / 6.0);
constexpr float F_IDX2 = (float)(1.0 / (5e-09 * 5e-09));
constexpr float F_2A   = (float)(2.0 * 1.3e-11);
constexpr float F_NMU0 = (float)(-(4e-07 * 3.14159265358979323846));
constexpr float F_CSOT = 0.001f;
constexpr float F_ALPHA= 0.02f;
constexpr float F_CLLG = (float)(-(1.0 / (1.0 + 0.02*0.02)));

struct V3 { float x, y, z; };

__device__ __forceinline__ V3 torque_llg(
    float mx, float my, float mz,
    float sux, float suy, float suz,
    float bx, float by, float bz, float cex, float dmg)
{
    const float lx = (sux - 4.0f*mx) * F_IDX2;
    const float ly = (suy - 4.0f*my) * F_IDX2;
    const float lz = (suz - 4.0f*mz) * F_IDX2;
    const float bex = bx + cex*lx;
    const float bey = by + cex*ly;
    const float bez = (bz + cex*lz) + dmg*mz;
    const float ax = my*bez - mz*bey;
    const float ay = mz*bex - mx*bez;
    const float az = mx*bey - my*bex;
    const float cx = my*az - mz*ay;
    const float cy = mz*ax - mx*az;
    const float cz = mx*ay - my*ax;
    // sot = C_SOT * (m x (m x p)), p=(0,1,0)
    const float sx = my*mx;
    const float sy = mz*(-mz) - mx*mx;
    const float sz = my*mz;
    V3 t;
    t.x = F_CLLG*(ax + F_ALPHA*cx) + F_CSOT*sx;
    t.y = F_CLLG*(ay + F_ALPHA*cy) + F_CSOT*sy;
    t.z = F_CLLG*(az + F_ALPHA*cz) + F_CSOT*sz;
    return t;
}

__global__ __launch_bounds__(NTHR, 1) void mm_persist(
    const float* __restrict__ signal, const float* __restrict__ B_ext,
    const float* __restrict__ Msat, const int* __restrict__ src_idx,
    const int* __restrict__ probe_idx, float* __restrict__ out,
    float* __restrict__ ws)
{
    __shared__ float mb[3][EXT][EXT];   // state at step start (pristine)
    __shared__ float ta[3][EXT][EXT];   // trial buffer A (k1-,k3-trial)
    __shared__ float tb2[3][EXT][EXT];  // trial buffer B (k2-trial)
    __shared__ float bxs[3][EXT][EXT];  // B_ext (time-invariant)
    __shared__ float mci[EXT][EXT];     // 2A/Msat
    __shared__ float mdg[EXT][EXT];     // -MU0*Msat
    __shared__ float ka[3][NTHR];       // RK4 accumulator
    __shared__ float sgl[2*T_STEPS];    // full signal, staged once

    const int tid = threadIdx.x;
    const int bid = blockIdx.x;
    const int br = bid / NBS, bc = bid - (bid/NBS)*NBS;
    const int r0 = br*TW, c0 = bc*TW;

    int* flags = (int*)(ws + 6*NPLANE);

    // ---- one-time staging ----
    for (int i = tid; i < 3*EXT*EXT; i += NTHR) {
        const int comp = i / (EXT*EXT);
        const int rem  = i - comp*(EXT*EXT);
        const int er = rem / EXT, ec = rem - (rem/EXT)*EXT;
        const int gr = min(max(r0 - HALO + er, 0), GNX-1);
        const int gc = min(max(c0 - HALO + ec, 0), GNX-1);
        bxs[comp][er][ec] = B_ext[comp*NPLANE + gr*GNX + gc];
        mb[comp][er][ec]  = (comp == 1) ? 1.0f : 0.0f;   // m0 = y-hat
    }
    for (int i = tid; i < EXT*EXT; i += NTHR) {
        const int er = i / EXT, ec = i - (i/EXT)*EXT;
        const int gr = min(max(r0 - HALO + er, 0), GNX-1);
        const int gc = min(max(c0 - HALO + ec, 0), GNX-1);
        const float ms = Msat[gr*GNX + gc];
        mci[er][ec] = F_2A / ms;
        mdg[er][ec] = F_NMU0 * ms;
    }
    for (int i = tid; i < 2*T_STEPS; i += NTHR) sgl[i] = signal[i];

    const int s0r = src_idx[0], s0c = src_idx[1];
    const int s1r = src_idx[2], s1c = src_idx[3];
    int pr[4], pc[4];
    #pragma unroll
    for (int j = 0; j < 4; ++j) { pr[j] = probe_idx[2*j]; pc[j] = probe_idx[2*j+1]; }

    const int ir_o = tid / TW, ic_o = tid - (tid/TW)*TW;
    const int gr_o = r0 + ir_o, gc_o = c0 + ic_o;
    const float msat_o = Msat[gr_o*GNX + gc_o];

    // my polled neighbor (threads 0..7), -1 if off-grid
    int my_nb = -1;
    if (tid < 8) {
        const int j  = (tid < 4) ? tid : tid + 1;   // skip center
        const int nr = br + j/3 - 1, nc = bc + (j - (j/3)*3) - 1;
        if (nr >= 0 && nr < NBS && nc >= 0 && nc < NBS) my_nb = nr*NBS + nc;
    }

    for (int tstep = 1; tstep <= T_STEPS; ++tstep) {
        float* mcur = ws + (tstep & 1) * 3*NPLANE;
        const float sg0 = sgl[2*(tstep-1) + 0];
        const float sg1 = sgl[2*(tstep-1) + 1];
        ka[0][tid] = 0.0f; ka[1][tid] = 0.0f; ka[2][tid] = 0.0f;

        if (tstep > 1) {
            // ---- wait for neighbors to publish state tstep-1 ----
            if (my_nb >= 0) {
                const int* fp = flags + my_nb*FSTR;
                while (__hip_atomic_load(fp, __ATOMIC_ACQUIRE,
                                         __HIP_MEMORY_SCOPE_AGENT) < tstep-1) {}
            }
            __syncthreads();
            // ---- reload halo ring from buf[(tstep-1)&1] ----
            const float* mprev = ws + ((tstep-1) & 1) * 3*NPLANE;
            for (int i = tid; i < 3*RING; i += NTHR) {
                const int comp = i / RING;
                const int r = i - comp*RING;
                int er, ec;
                if (r < 4*EXT) {                       // top 4 rows
                    er = r / EXT; ec = r - (r/EXT)*EXT;
                } else if (r < 8*EXT) {                // bottom 4 rows
                    const int q = r - 4*EXT;
                    er = (EXT-4) + q / EXT; ec = q - (q/EXT)*EXT;
                } else {                               // side bands
                    const int q = r - 8*EXT;
                    er = HALO + (q >> 3);
                    const int c = q & 7;
                    ec = (c < 4) ? c : (TW + c);
                }
                const int gr = min(max(r0 - HALO + er, 0), GNX-1);
                const int gc = min(max(c0 - HALO + ec, 0), GNX-1);
                mb[comp][er][ec] = mprev[comp*NPLANE + gr*GNX + gc];
            }
        }
        __syncthreads();   // ring + ka zero visible

        // ---- 4 RK4 substeps, shrinking regions, 1 barrier each ----
        #pragma unroll
        for (int k = 0; k < 4; ++k) {
            const int W   = 22 - 2*k;            // 22,20,18,16
            const int off = (EXT - W) / 2;
            const float wk = (k == 1 || k == 2) ? 2.0f : 1.0f;
            const float cc = (k == 2) ? 1.0f : 0.5f;

            float (*rd)[EXT][EXT] = (k == 0) ? mb : ((k == 2) ? tb2 : ta);
            float (*wr)[EXT][EXT] = (k == 1) ? tb2 : ta;

            for (int i = tid; i < W*W; i += NTHR) {
                const int er = off + i / W;
                const int ec = off + (i - (i/W)*W);
                const int gr = r0 - HALO + er, gc = c0 - HALO + ec;
                if (gr < 0 || gr >= GNX || gc < 0 || gc >= GNX) continue;

                const int eru = (gr == 0)      ? er : er - 1;
                const int erd = (gr == GNX-1)  ? er : er + 1;
                const int ecl = (gc == 0)      ? ec : ec - 1;
                const int ecr = (gc == GNX-1)  ? ec : ec + 1;

                const float mx = rd[0][er][ec], my = rd[1][er][ec], mz = rd[2][er][ec];
                const float sux = ((rd[0][erd][ec] + rd[0][eru][ec]) + rd[0][er][ecr]) + rd[0][er][ecl];
                const float suy = ((rd[1][erd][ec] + rd[1][eru][ec]) + rd[1][er][ecr]) + rd[1][er][ecl];
                const float suz = ((rd[2][erd][ec] + rd[2][eru][ec]) + rd[2][er][ecr]) + rd[2][er][ecl];

                float bz = bxs[2][er][ec];
                if (gr == s0r && gc == s0c) bz = sg0;
                if (gr == s1r && gc == s1c) bz = sg1;

                const V3 tq = torque_llg(mx, my, mz, sux, suy, suz,
                                         bxs[0][er][ec], bxs[1][er][ec], bz,
                                         mci[er][ec], mdg[er][ec]);

                const int ir = er - HALO, ic = ec - HALO;
                if (ir >= 0 && ir < TW && ic >= 0 && ic < TW) {
                    const int idx = ir*TW + ic;
                    ka[0][idx] += wk*tq.x;
                    ka[1][idx] += wk*tq.y;
                    ka[2][idx] += wk*tq.z;
                }
                if (k < 3) {
                    wr[0][er][ec] = mb[0][er][ec] + (F_H*tq.x)*cc;
                    wr[1][er][ec] = mb[1][er][ec] + (F_H*tq.y)*cc;
                    wr[2][er][ec] = mb[2][er][ec] + (F_H*tq.z)*cc;
                }
            }
            __syncthreads();
        }

        // ---- final update: own interior cell; refresh LDS + global ----
        {
            const int er = HALO + ir_o, ec = HALO + ic_o;
            const float nx = mb[0][er][ec] + F_H6 * ka[0][tid];
            const float ny = mb[1][er][ec] + F_H6 * ka[1][tid];
            const float nz = mb[2][er][ec] + F_H6 * ka[2][tid];
            mb[0][er][ec] = nx; mb[1][er][ec] = ny; mb[2][er][ec] = nz;
            mcur[0*NPLANE + gr_o*GNX + gc_o] = nx;
            mcur[1*NPLANE + gr_o*GNX + gc_o] = ny;
            mcur[2*NPLANE + gr_o*GNX + gc_o] = nz;
            #pragma unroll
            for (int j = 0; j < 4; ++j) {
                if (gr_o == pr[j] && gc_o == pc[j]) {
                    out[(tstep-1)*4 + j] = nz * msat_o;   // m0_z == 0 exactly
                }
            }
        }

        // ---- publish: all writes agent-visible, then release flag ----
        __threadfence();
        __syncthreads();
        if (tid == 0) {
            __hip_atomic_store(flags + bid*FSTR, tstep, __ATOMIC_RELEASE,
                               __HIP_MEMORY_SCOPE_AGENT);
        }
    }
}

extern "C" void kernel_launch(void* const* d_in, const int* in_sizes, int n_in,
                              void* d_out, int out_size, void* d_ws, size_t ws_size,
                              hipStream_t stream) {
    const float* sig  = (const float*)d_in[0];
    const float* Bex  = (const float*)d_in[1];
    const float* Ms   = (const float*)d_in[2];
    const int*   srci = (const int*)d_in[3];
    const int*   prbi = (const int*)d_in[4];
    float* out = (float*)d_out;
    float* ws  = (float*)d_ws;

    void* args[] = { (void*)&sig, (void*)&Bex, (void*)&Ms,
                     (void*)&srci, (void*)&prbi, (void*)&out, (void*)&ws };
    hipLaunchCooperativeKernel((const void*)mm_persist, dim3(NBLK), dim3(NTHR),
                               args, 0, stream);
}

// Round 4
// 1599.755 us; speedup vs baseline: 2.4320x; 1.9191x over previous
//
#include <hip/hip_runtime.h>

// Micromagnetic LLG + RK4, 128x128 grid, 256 signal steps.
// Exact simplifications (verified R0-R2, absmax ~2e-31):
//  - 100 relaxation steps are a bit-exact no-op => m0 = y-hat, m0_z = 0.
//  - probe value = mz_new * Msat.
//
// R3: persistent kernel, p2p neighbor sync WITHOUT cache-wide fences.
// R2 showed __threadfence (L2 writeback) + acquire (L2 invalidate) cost
// ~10us/step and forced 348KB/step of refetch. Now all cross-block data
// (halo ring cells + progress flags) moves via per-access coherent ops:
//   writer: __hip_atomic_store(RELAXED, AGENT)  -> write-through, no L2 dirty
//   order:  __syncthreads() drains vmcnt(0) => data at coherence point
//   flag:   relaxed agent store AFTER the barrier
//   reader: poll flag (relaxed agent load), __syncthreads, ring loads
//           (relaxed agent loads, bypass stale L1/L2)
// Double-buffered ring planes bound neighbor skew to 1 step (same proof as
// R2), so one wait per step is race-free. ws 0xAA poison = negative int
// flag => safe spin without pre-zeroing.

#define GNX 128
#define NPLANE (GNX*GNX)
#define T_STEPS 256

constexpr int TW   = 16;
constexpr int HALO = 4;
constexpr int EXT  = TW + 2*HALO;    // 24
constexpr int NBS  = GNX / TW;       // 8
constexpr int NBLK = NBS * NBS;      // 64
constexpr int NTHR = 256;
constexpr int RING = EXT*EXT - TW*TW;  // 320
constexpr int FSTR = 32;             // flag stride in ints (128 B apart)

constexpr float F_H    = (float)(175950000000.0 * 1e-13);            // GAMMA*DT
constexpr float F_H6   = (float)(175950000000.0 * 1e-13 / 6.0);
constexpr float F_IDX2 = (float)(1.0 / (5e-09 * 5e-09));
constexpr float F_2A   = (float)(2.0 * 1.3e-11);
constexpr float F_NMU0 = (float)(-(4e-07 * 3.14159265358979323846));
constexpr float F_CSOT = 0.001f;
constexpr float F_ALPHA= 0.02f;
constexpr float F_CLLG = (float)(-(1.0 / (1.0 + 0.02*0.02)));

struct V3 { float x, y, z; };

__device__ __forceinline__ float ld_coh(const float* p) {
    return __hip_atomic_load(p, __ATOMIC_RELAXED, __HIP_MEMORY_SCOPE_AGENT);
}
__device__ __forceinline__ void st_coh(float* p, float v) {
    __hip_atomic_store(p, v, __ATOMIC_RELAXED, __HIP_MEMORY_SCOPE_AGENT);
}

__device__ __forceinline__ V3 torque_llg(
    float mx, float my, float mz,
    float sux, float suy, float suz,
    float bx, float by, float bz, float cex, float dmg)
{
    const float lx = (sux - 4.0f*mx) * F_IDX2;
    const float ly = (suy - 4.0f*my) * F_IDX2;
    const float lz = (suz - 4.0f*mz) * F_IDX2;
    const float bex = bx + cex*lx;
    const float bey = by + cex*ly;
    const float bez = (bz + cex*lz) + dmg*mz;
    const float ax = my*bez - mz*bey;
    const float ay = mz*bex - mx*bez;
    const float az = mx*bey - my*bex;
    const float cx = my*az - mz*ay;
    const float cy = mz*ax - mx*az;
    const float cz = mx*ay - my*ax;
    // sot = C_SOT * (m x (m x p)), p=(0,1,0)
    const float sx = my*mx;
    const float sy = mz*(-mz) - mx*mx;
    const float sz = my*mz;
    V3 t;
    t.x = F_CLLG*(ax + F_ALPHA*cx) + F_CSOT*sx;
    t.y = F_CLLG*(ay + F_ALPHA*cy) + F_CSOT*sy;
    t.z = F_CLLG*(az + F_ALPHA*cz) + F_CSOT*sz;
    return t;
}

__global__ __launch_bounds__(NTHR, 1) void mm_persist(
    const float* __restrict__ signal, const float* __restrict__ B_ext,
    const float* __restrict__ Msat, const int* __restrict__ src_idx,
    const int* __restrict__ probe_idx, float* __restrict__ out,
    float* __restrict__ ws)
{
    __shared__ float mb[3][EXT][EXT];   // state at step start (pristine)
    __shared__ float ta[3][EXT][EXT];   // trial buffer A
    __shared__ float tb2[3][EXT][EXT];  // trial buffer B
    __shared__ float bxs[3][EXT][EXT];  // B_ext (time-invariant)
    __shared__ float mci[EXT][EXT];     // 2A/Msat
    __shared__ float mdg[EXT][EXT];     // -MU0*Msat
    __shared__ float ka[3][NTHR];       // RK4 accumulator
    __shared__ float sgl[2*T_STEPS];    // full signal, staged once

    const int tid = threadIdx.x;
    const int bid = blockIdx.x;
    const int br = bid / NBS, bc = bid - (bid/NBS)*NBS;
    const int r0 = br*TW, c0 = bc*TW;

    int* flags = (int*)(ws + 6*NPLANE);

    // ---- one-time staging ----
    for (int i = tid; i < 3*EXT*EXT; i += NTHR) {
        const int comp = i / (EXT*EXT);
        const int rem  = i - comp*(EXT*EXT);
        const int er = rem / EXT, ec = rem - (rem/EXT)*EXT;
        const int gr = min(max(r0 - HALO + er, 0), GNX-1);
        const int gc = min(max(c0 - HALO + ec, 0), GNX-1);
        bxs[comp][er][ec] = B_ext[comp*NPLANE + gr*GNX + gc];
        mb[comp][er][ec]  = (comp == 1) ? 1.0f : 0.0f;   // m0 = y-hat
    }
    for (int i = tid; i < EXT*EXT; i += NTHR) {
        const int er = i / EXT, ec = i - (i/EXT)*EXT;
        const int gr = min(max(r0 - HALO + er, 0), GNX-1);
        const int gc = min(max(c0 - HALO + ec, 0), GNX-1);
        const float ms = Msat[gr*GNX + gc];
        mci[er][ec] = F_2A / ms;
        mdg[er][ec] = F_NMU0 * ms;
    }
    for (int i = tid; i < 2*T_STEPS; i += NTHR) sgl[i] = signal[i];

    const int s0r = src_idx[0], s0c = src_idx[1];
    const int s1r = src_idx[2], s1c = src_idx[3];
    int pr[4], pc[4];
    #pragma unroll
    for (int j = 0; j < 4; ++j) { pr[j] = probe_idx[2*j]; pc[j] = probe_idx[2*j+1]; }

    const int ir_o = tid / TW, ic_o = tid - (tid/TW)*TW;
    const int gr_o = r0 + ir_o, gc_o = c0 + ic_o;
    const float msat_o = Msat[gr_o*GNX + gc_o];
    // does my interior cell belong to the published band (within 4 of edge)?
    const int in_band = (ir_o < HALO) | (ir_o >= TW-HALO) |
                        (ic_o < HALO) | (ic_o >= TW-HALO);

    // my polled neighbor (threads 0..7), -1 if off-grid
    int my_nb = -1;
    if (tid < 8) {
        const int j  = (tid < 4) ? tid : tid + 1;   // skip center
        const int nr = br + j/3 - 1, nc = bc + (j - (j/3)*3) - 1;
        if (nr >= 0 && nr < NBS && nc >= 0 && nc < NBS) my_nb = nr*NBS + nc;
    }

    for (int tstep = 1; tstep <= T_STEPS; ++tstep) {
        float* mcur = ws + (tstep & 1) * 3*NPLANE;
        const float sg0 = sgl[2*(tstep-1) + 0];
        const float sg1 = sgl[2*(tstep-1) + 1];
        ka[0][tid] = 0.0f; ka[1][tid] = 0.0f; ka[2][tid] = 0.0f;

        if (tstep > 1) {
            // ---- wait for neighbors to publish state tstep-1 ----
            if (my_nb >= 0) {
                const int* fp = flags + my_nb*FSTR;
                while (__hip_atomic_load(fp, __ATOMIC_RELAXED,
                                         __HIP_MEMORY_SCOPE_AGENT) < tstep-1) {}
            }
            __syncthreads();
            // ---- reload halo ring from buf[(tstep-1)&1], coherent loads ----
            const float* mprev = ws + ((tstep-1) & 1) * 3*NPLANE;
            for (int i = tid; i < 3*RING; i += NTHR) {
                const int comp = i / RING;
                const int r = i - comp*RING;
                int er, ec;
                if (r < 4*EXT) {                       // top 4 rows
                    er = r / EXT; ec = r - (r/EXT)*EXT;
                } else if (r < 8*EXT) {                // bottom 4 rows
                    const int q = r - 4*EXT;
                    er = (EXT-4) + q / EXT; ec = q - (q/EXT)*EXT;
                } else {                               // side bands
                    const int q = r - 8*EXT;
                    er = HALO + (q >> 3);
                    const int c = q & 7;
                    ec = (c < 4) ? c : (TW + c);
                }
                const int gr = min(max(r0 - HALO + er, 0), GNX-1);
                const int gc = min(max(c0 - HALO + ec, 0), GNX-1);
                mb[comp][er][ec] = ld_coh(&mprev[comp*NPLANE + gr*GNX + gc]);
            }
        }
        __syncthreads();   // ring + ka zero visible

        // ---- 4 RK4 substeps, shrinking regions, 1 barrier each ----
        #pragma unroll
        for (int k = 0; k < 4; ++k) {
            const int W   = 22 - 2*k;            // 22,20,18,16
            const int off = (EXT - W) / 2;
            const float wk = (k == 1 || k == 2) ? 2.0f : 1.0f;
            const float cc = (k == 2) ? 1.0f : 0.5f;

            float (*rd)[EXT][EXT] = (k == 0) ? mb : ((k == 2) ? tb2 : ta);
            float (*wr)[EXT][EXT] = (k == 1) ? tb2 : ta;

            for (int i = tid; i < W*W; i += NTHR) {
                const int er = off + i / W;
                const int ec = off + (i - (i/W)*W);
                const int gr = r0 - HALO + er, gc = c0 - HALO + ec;
                if (gr < 0 || gr >= GNX || gc < 0 || gc >= GNX) continue;

                const int eru = (gr == 0)      ? er : er - 1;
                const int erd = (gr == GNX-1)  ? er : er + 1;
                const int ecl = (gc == 0)      ? ec : ec - 1;
                const int ecr = (gc == GNX-1)  ? ec : ec + 1;

                const float mx = rd[0][er][ec], my = rd[1][er][ec], mz = rd[2][er][ec];
                const float sux = ((rd[0][erd][ec] + rd[0][eru][ec]) + rd[0][er][ecr]) + rd[0][er][ecl];
                const float suy = ((rd[1][erd][ec] + rd[1][eru][ec]) + rd[1][er][ecr]) + rd[1][er][ecl];
                const float suz = ((rd[2][erd][ec] + rd[2][eru][ec]) + rd[2][er][ecr]) + rd[2][er][ecl];

                float bz = bxs[2][er][ec];
                if (gr == s0r && gc == s0c) bz = sg0;
                if (gr == s1r && gc == s1c) bz = sg1;

                const V3 tq = torque_llg(mx, my, mz, sux, suy, suz,
                                         bxs[0][er][ec], bxs[1][er][ec], bz,
                                         mci[er][ec], mdg[er][ec]);

                const int ir = er - HALO, ic = ec - HALO;
                if (ir >= 0 && ir < TW && ic >= 0 && ic < TW) {
                    const int idx = ir*TW + ic;
                    ka[0][idx] += wk*tq.x;
                    ka[1][idx] += wk*tq.y;
                    ka[2][idx] += wk*tq.z;
                }
                if (k < 3) {
                    wr[0][er][ec] = mb[0][er][ec] + (F_H*tq.x)*cc;
                    wr[1][er][ec] = mb[1][er][ec] + (F_H*tq.y)*cc;
                    wr[2][er][ec] = mb[2][er][ec] + (F_H*tq.z)*cc;
                }
            }
            __syncthreads();
        }

        // ---- final update: own interior cell; publish band coherently ----
        {
            const int er = HALO + ir_o, ec = HALO + ic_o;
            const float nx = mb[0][er][ec] + F_H6 * ka[0][tid];
            const float ny = mb[1][er][ec] + F_H6 * ka[1][tid];
            const float nz = mb[2][er][ec] + F_H6 * ka[2][tid];
            mb[0][er][ec] = nx; mb[1][er][ec] = ny; mb[2][er][ec] = nz;
            if (in_band) {
                st_coh(&mcur[0*NPLANE + gr_o*GNX + gc_o], nx);
                st_coh(&mcur[1*NPLANE + gr_o*GNX + gc_o], ny);
                st_coh(&mcur[2*NPLANE + gr_o*GNX + gc_o], nz);
            }
            #pragma unroll
            for (int j = 0; j < 4; ++j) {
                if (gr_o == pr[j] && gc_o == pc[j]) {
                    out[(tstep-1)*4 + j] = nz * msat_o;   // m0_z == 0 exactly
                }
            }
        }

        // __syncthreads drains vmcnt(0): band stores have reached the
        // coherence point before the flag becomes visible.
        __syncthreads();
        if (tid == 0) {
            __hip_atomic_store(flags + bid*FSTR, tstep, __ATOMIC_RELAXED,
                               __HIP_MEMORY_SCOPE_AGENT);
        }
    }
}

extern "C" void kernel_launch(void* const* d_in, const int* in_sizes, int n_in,
                              void* d_out, int out_size, void* d_ws, size_t ws_size,
                              hipStream_t stream) {
    const float* sig  = (const float*)d_in[0];
    const float* Bex  = (const float*)d_in[1];
    const float* Ms   = (const float*)d_in[2];
    const int*   srci = (const int*)d_in[3];
    const int*   prbi = (const int*)d_in[4];
    float* out = (float*)d_out;
    float* ws  = (float*)d_ws;

    void* args[] = { (void*)&sig, (void*)&Bex, (void*)&Ms,
                     (void*)&srci, (void*)&prbi, (void*)&out, (void*)&ws };
    hipLaunchCooperativeKernel((const void*)mm_persist, dim3(NBLK), dim3(NTHR),
                               args, 0, stream);
}

// Round 5
// 1017.661 us; speedup vs baseline: 3.8231x; 1.5720x over previous
//
#include <hip/hip_runtime.h>

// Micromagnetic LLG + RK4, 128x128 grid, 256 signal steps.
// Exact simplifications (verified R0-R3, absmax ~2e-31):
//  - 100 relaxation steps are a bit-exact no-op => m0 = y-hat, m0_z = 0.
//  - probe value = mz_new * Msat.
//
// R4: two levers on top of R3's sc1 p2p exchange (which gave 6.0us/step):
//  1. K=2 step fusion per exchange epoch: halo-8 tiles (EXT=32), 8 RK4
//     substeps on shrinking regions 30..16. Step A produces m_mid on a
//     24x24 region (interior 16 + halo 4), step B consumes it locally.
//     => 128 exchanges instead of 256.
//  2. 1024 threads/block (16 waves/CU, 4/SIMD instead of 1/SIMD): every
//     substep is ONE pass (<=900 cells), and multi-wave occupancy hides
//     LDS/L3 latency that R3 (1 wave/SIMD) fully exposed.
// Cross-block data still moves via per-access coherent (sc1) ops + relaxed
// agent-scope flags; double-buffered ring planes bound skew to 1 epoch.
// ws 0xAA poison = negative flag => safe spin without pre-zeroing.

#define GNX 128
#define NPLANE (GNX*GNX)
#define T_STEPS 256
#define NEPOCH 128

constexpr int TW   = 16;
constexpr int HALO = 8;
constexpr int EXT  = TW + 2*HALO;      // 32
constexpr int NBS  = GNX / TW;         // 8
constexpr int NBLK = NBS * NBS;        // 64
constexpr int NTHR = 1024;
constexpr int RING = EXT*EXT - TW*TW;  // 768
constexpr int FSTR = 32;               // flag stride in ints

constexpr float F_H    = (float)(175950000000.0 * 1e-13);            // GAMMA*DT
constexpr float F_H6   = (float)(175950000000.0 * 1e-13 / 6.0);
constexpr float F_IDX2 = (float)(1.0 / (5e-09 * 5e-09));
constexpr float F_2A   = (float)(2.0 * 1.3e-11);
constexpr float F_NMU0 = (float)(-(4e-07 * 3.14159265358979323846));
constexpr float F_CSOT = 0.001f;
constexpr float F_ALPHA= 0.02f;
constexpr float F_CLLG = (float)(-(1.0 / (1.0 + 0.02*0.02)));

struct V3 { float x, y, z; };

__device__ __forceinline__ float ld_coh(const float* p) {
    return __hip_atomic_load(p, __ATOMIC_RELAXED, __HIP_MEMORY_SCOPE_AGENT);
}
__device__ __forceinline__ void st_coh(float* p, float v) {
    __hip_atomic_store(p, v, __ATOMIC_RELAXED, __HIP_MEMORY_SCOPE_AGENT);
}

__device__ __forceinline__ V3 torque_llg(
    float mx, float my, float mz,
    float sux, float suy, float suz,
    float bx, float by, float bz, float cex, float dmg)
{
    const float lx = (sux - 4.0f*mx) * F_IDX2;
    const float ly = (suy - 4.0f*my) * F_IDX2;
    const float lz = (suz - 4.0f*mz) * F_IDX2;
    const float bex = bx + cex*lx;
    const float bey = by + cex*ly;
    const float bez = (bz + cex*lz) + dmg*mz;
    const float ax = my*bez - mz*bey;
    const float ay = mz*bex - mx*bez;
    const float az = mx*bey - my*bex;
    const float cx = my*az - mz*ay;
    const float cy = mz*ax - mx*az;
    const float cz = mx*ay - my*ax;
    // sot = C_SOT * (m x (m x p)), p=(0,1,0)
    const float sx = my*mx;
    const float sy = mz*(-mz) - mx*mx;
    const float sz = my*mz;
    V3 t;
    t.x = F_CLLG*(ax + F_ALPHA*cx) + F_CSOT*sx;
    t.y = F_CLLG*(ay + F_ALPHA*cy) + F_CSOT*sy;
    t.z = F_CLLG*(az + F_ALPHA*cz) + F_CSOT*sz;
    return t;
}

__global__ __launch_bounds__(NTHR, 1) void mm_persist(
    const float* __restrict__ signal, const float* __restrict__ B_ext,
    const float* __restrict__ Msat, const int* __restrict__ src_idx,
    const int* __restrict__ probe_idx, float* __restrict__ out,
    float* __restrict__ ws)
{
    __shared__ float mb[3][EXT][EXT];   // state at epoch start / m_mid
    __shared__ float ta[3][EXT][EXT];   // trial buffer A
    __shared__ float tb2[3][EXT][EXT];  // trial buffer B
    __shared__ float bxs[3][EXT][EXT];  // B_ext (time-invariant)
    __shared__ float mci[EXT][EXT];     // 2A/Msat
    __shared__ float mdg[EXT][EXT];     // -MU0*Msat
    __shared__ float ka[3][24*24];      // RK4 accumulator (A: 24^2, B: 16^2)
    __shared__ float sgl[2*T_STEPS];    // full signal, staged once

    const int tid = threadIdx.x;
    const int bid = blockIdx.x;
    const int br = bid / NBS, bc = bid - (bid/NBS)*NBS;
    const int r0 = br*TW, c0 = bc*TW;

    int* flags = (int*)(ws + 6*NPLANE);

    // ---- one-time staging ----
    for (int i = tid; i < 3*EXT*EXT; i += NTHR) {
        const int comp = i / (EXT*EXT);
        const int rem  = i - comp*(EXT*EXT);
        const int er = rem / EXT, ec = rem - (rem/EXT)*EXT;
        const int gr = min(max(r0 - HALO + er, 0), GNX-1);
        const int gc = min(max(c0 - HALO + ec, 0), GNX-1);
        bxs[comp][er][ec] = B_ext[comp*NPLANE + gr*GNX + gc];
        mb[comp][er][ec]  = (comp == 1) ? 1.0f : 0.0f;   // m0 = y-hat
    }
    for (int i = tid; i < EXT*EXT; i += NTHR) {
        const int er = i / EXT, ec = i - (i/EXT)*EXT;
        const int gr = min(max(r0 - HALO + er, 0), GNX-1);
        const int gc = min(max(c0 - HALO + ec, 0), GNX-1);
        const float ms = Msat[gr*GNX + gc];
        mci[er][ec] = F_2A / ms;
        mdg[er][ec] = F_NMU0 * ms;
    }
    for (int i = tid; i < 2*T_STEPS; i += NTHR) sgl[i] = signal[i];
    for (int i = tid; i < 24*24; i += NTHR) {
        ka[0][i] = 0.0f; ka[1][i] = 0.0f; ka[2][i] = 0.0f;
    }

    const int s0r = src_idx[0], s0c = src_idx[1];
    const int s1r = src_idx[2], s1c = src_idx[3];
    int pr[4], pc[4];
    #pragma unroll
    for (int j = 0; j < 4; ++j) { pr[j] = probe_idx[2*j]; pc[j] = probe_idx[2*j+1]; }

    // my polled neighbor (threads 0..7), -1 if off-grid
    int my_nb = -1;
    if (tid < 8) {
        const int j  = (tid < 4) ? tid : tid + 1;   // skip center
        const int nr = br + j/3 - 1, nc = bc + (j - (j/3)*3) - 1;
        if (nr >= 0 && nr < NBS && nc >= 0 && nc < NBS) my_nb = nr*NBS + nc;
    }

    for (int e = 0; e < NEPOCH; ++e) {
        float* mcur = ws + (e & 1) * 3*NPLANE;

        if (e > 0) {
            // wait for neighbors to have completed epoch e-1
            if (my_nb >= 0) {
                const int* fp = flags + my_nb*FSTR;
                while (__hip_atomic_load(fp, __ATOMIC_RELAXED,
                                         __HIP_MEMORY_SCOPE_AGENT) < e) {}
            }
            __syncthreads();
            // reload full halo ring (768 cells x 3 comps), coherent loads
            const float* mprev = ws + ((e + 1) & 1) * 3*NPLANE;
            for (int i = tid; i < 3*RING; i += NTHR) {
                const int comp = i / RING;
                const int r = i - comp*RING;
                int er, ec;
                if (r < 8*EXT) {                       // top 8 rows
                    er = r / EXT; ec = r - (r/EXT)*EXT;
                } else if (r < 16*EXT) {               // bottom 8 rows
                    const int q = r - 8*EXT;
                    er = (EXT-8) + q / EXT; ec = q - (q/EXT)*EXT;
                } else {                               // side bands, rows 8..23
                    const int q = r - 16*EXT;
                    er = HALO + (q >> 4);
                    const int c = q & 15;
                    ec = (c < 8) ? c : (TW + c);
                }
                const int gr = min(max(r0 - HALO + er, 0), GNX-1);
                const int gc = min(max(c0 - HALO + ec, 0), GNX-1);
                mb[comp][er][ec] = ld_coh(&mprev[comp*NPLANE + gr*GNX + gc]);
            }
        }
        __syncthreads();   // staging (e=0) / ring (e>0) visible

        // ---- two fused RK4 steps: p=0 (step 2e), p=1 (step 2e+1) ----
        #pragma unroll
        for (int p = 0; p < 2; ++p) {
            const float sg0 = sgl[4*e + 2*p + 0];
            const float sg1 = sgl[4*e + 2*p + 1];
            const int KO = p ? 8 : 4;          // ka region offset
            const int KW = p ? 16 : 24;        // ka region width

            #pragma unroll
            for (int k = 0; k < 4; ++k) {
                const int W   = (p ? 22 : 30) - 2*k;
                const int off = (EXT - W) / 2;
                const float wk = (k == 1 || k == 2) ? 2.0f : 1.0f;
                const float cc = (k == 2) ? 1.0f : 0.5f;

                float (*rd)[EXT][EXT] = (k == 0) ? mb : ((k == 2) ? tb2 : ta);
                float (*wr)[EXT][EXT] = (k == 1) ? tb2 : ta;

                if (tid < W*W) {
                    const int er = off + tid / W;
                    const int ec = off + (tid - (tid/W)*W);
                    const int gr = r0 - HALO + er, gc = c0 - HALO + ec;
                    if (gr >= 0 && gr < GNX && gc >= 0 && gc < GNX) {
                        const int eru = (gr == 0)      ? er : er - 1;
                        const int erd = (gr == GNX-1)  ? er : er + 1;
                        const int ecl = (gc == 0)      ? ec : ec - 1;
                        const int ecr = (gc == GNX-1)  ? ec : ec + 1;

                        const float mx = rd[0][er][ec], my = rd[1][er][ec], mz = rd[2][er][ec];
                        const float sux = ((rd[0][erd][ec] + rd[0][eru][ec]) + rd[0][er][ecr]) + rd[0][er][ecl];
                        const float suy = ((rd[1][erd][ec] + rd[1][eru][ec]) + rd[1][er][ecr]) + rd[1][er][ecl];
                        const float suz = ((rd[2][erd][ec] + rd[2][eru][ec]) + rd[2][er][ecr]) + rd[2][er][ecl];

                        float bz = bxs[2][er][ec];
                        if (gr == s0r && gc == s0c) bz = sg0;
                        if (gr == s1r && gc == s1c) bz = sg1;

                        const V3 tq = torque_llg(mx, my, mz, sux, suy, suz,
                                                 bxs[0][er][ec], bxs[1][er][ec], bz,
                                                 mci[er][ec], mdg[er][ec]);

                        if (er >= KO && er < KO+KW && ec >= KO && ec < KO+KW) {
                            const int idx = (er - KO)*KW + (ec - KO);
                            ka[0][idx] += wk*tq.x;
                            ka[1][idx] += wk*tq.y;
                            ka[2][idx] += wk*tq.z;
                        }
                        if (k < 3) {
                            wr[0][er][ec] = mb[0][er][ec] + (F_H*tq.x)*cc;
                            wr[1][er][ec] = mb[1][er][ec] + (F_H*tq.y)*cc;
                            wr[2][er][ec] = mb[2][er][ec] + (F_H*tq.z)*cc;
                        }
                    }
                }
                __syncthreads();
            }

            if (p == 0) {
                // ---- m_mid = mb + H/6*ka on the 24x24 region; rezero ka ----
                if (tid < 24*24) {
                    const int er = 4 + tid / 24, ec = 4 + tid - (tid/24)*24;
                    const float nx = mb[0][er][ec] + F_H6 * ka[0][tid];
                    const float ny = mb[1][er][ec] + F_H6 * ka[1][tid];
                    const float nz = mb[2][er][ec] + F_H6 * ka[2][tid];
                    mb[0][er][ec] = nx; mb[1][er][ec] = ny; mb[2][er][ec] = nz;
                    ka[0][tid] = 0.0f; ka[1][tid] = 0.0f; ka[2][tid] = 0.0f;
                    if (er >= HALO && er < HALO+TW && ec >= HALO && ec < HALO+TW) {
                        const int gr = r0 - HALO + er, gc = c0 - HALO + ec;
                        #pragma unroll
                        for (int j = 0; j < 4; ++j) {
                            if (gr == pr[j] && gc == pc[j]) {
                                out[(2*e)*4 + j] = nz * Msat[gr*GNX + gc];
                            }
                        }
                    }
                }
                __syncthreads();
            } else {
                // ---- final: interior update, coherent publish, probes ----
                if (tid < TW*TW) {
                    const int ir = tid / TW, ic = tid - (tid/TW)*TW;
                    const int er = HALO + ir, ec = HALO + ic;
                    const int gr = r0 + ir, gc = c0 + ic;
                    const float nx = mb[0][er][ec] + F_H6 * ka[0][tid];
                    const float ny = mb[1][er][ec] + F_H6 * ka[1][tid];
                    const float nz = mb[2][er][ec] + F_H6 * ka[2][tid];
                    mb[0][er][ec] = nx; mb[1][er][ec] = ny; mb[2][er][ec] = nz;
                    ka[0][tid] = 0.0f; ka[1][tid] = 0.0f; ka[2][tid] = 0.0f;
                    st_coh(&mcur[0*NPLANE + gr*GNX + gc], nx);
                    st_coh(&mcur[1*NPLANE + gr*GNX + gc], ny);
                    st_coh(&mcur[2*NPLANE + gr*GNX + gc], nz);
                    #pragma unroll
                    for (int j = 0; j < 4; ++j) {
                        if (gr == pr[j] && gc == pc[j]) {
                            out[(2*e+1)*4 + j] = nz * Msat[gr*GNX + gc];
                        }
                    }
                }
                // __syncthreads drains vmcnt(0): publish stores are at the
                // coherence point before the flag becomes visible.
                __syncthreads();
                if (tid == 0) {
                    __hip_atomic_store(flags + bid*FSTR, e + 1, __ATOMIC_RELAXED,
                                       __HIP_MEMORY_SCOPE_AGENT);
                }
            }
        }
    }
}

extern "C" void kernel_launch(void* const* d_in, const int* in_sizes, int n_in,
                              void* d_out, int out_size, void* d_ws, size_t ws_size,
                              hipStream_t stream) {
    const float* sig  = (const float*)d_in[0];
    const float* Bex  = (const float*)d_in[1];
    const float* Ms   = (const float*)d_in[2];
    const int*   srci = (const int*)d_in[3];
    const int*   prbi = (const int*)d_in[4];
    float* out = (float*)d_out;
    float* ws  = (float*)d_ws;

    void* args[] = { (void*)&sig, (void*)&Bex, (void*)&Ms,
                     (void*)&srci, (void*)&prbi, (void*)&out, (void*)&ws };
    hipLaunchCooperativeKernel((const void*)mm_persist, dim3(NBLK), dim3(NTHR),
                               args, 0, stream);
}

// Round 7
// 764.667 us; speedup vs baseline: 5.0880x; 1.3309x over previous
//
#include <hip/hip_runtime.h>

// Micromagnetic LLG + RK4, 128x128 grid, 256 signal steps.
// Exact simplifications (verified R0-R4, absmax ~2e-31):
//  - 100 relaxation steps are a bit-exact no-op => m0 = y-hat, m0_z = 0.
//  - probe value = mz_new * Msat.
//
// R6 = R5 structure + accumulator-lifetime fix.
//  R5 bug: register RK4 accumulator was fed by EVERY active cell (dd>k);
//  cells with dd in [5,8) accumulated during k=4..6 but never hit the k==7
//  reset, leaking stale k-sums into the next epoch's k==3 mid-update.
//  Fix: accumulate only when the sum will be consumed before its reset:
//  gate with dd > (k|3)  (k=0..3 -> dd>3 = mid-update users; k=4..7 ->
//  dd>7 = final users). Matches R4's LDS-ka zeroing semantics exactly.
//
// Structure (R5): fixed thread<->cell mapping, 1024 thr == 32x32 halo-8
// tile, K=2 fused steps/epoch, 128 epochs. LDS = 3 float4 trial planes;
// stencil = 4x ds_read_b128 + 1x ds_write_b128; base m, B_ext, Msat
// coeffs, RK4 accum in registers. Exchange via sc1 agent-scope per-access
// coherent ops + relaxed flags (proven R3/R4); double buffering bounds
// skew to 1 epoch; ws 0xAA poison = negative flag => safe spin.

#define GNX 128
#define NPLANE (GNX*GNX)
#define T_STEPS 256
#define NEPOCH 128

constexpr int NBS  = 8;
constexpr int NBLK = 64;
constexpr int NTHR = 1024;
constexpr int FSTR = 32;               // flag stride in ints

constexpr float F_H    = (float)(175950000000.0 * 1e-13);            // GAMMA*DT
constexpr float F_H6   = (float)(175950000000.0 * 1e-13 / 6.0);
constexpr float F_IDX2 = (float)(1.0 / (5e-09 * 5e-09));
constexpr float F_2A   = (float)(2.0 * 1.3e-11);
constexpr float F_NMU0 = (float)(-(4e-07 * 3.14159265358979323846));
constexpr float F_CSOT = 0.001f;
constexpr float F_ALPHA= 0.02f;
constexpr float F_CLLG = (float)(-(1.0 / (1.0 + 0.02*0.02)));

struct V3 { float x, y, z; };

__device__ __forceinline__ float ld_coh_f32(const float* p) {
    return __hip_atomic_load(p, __ATOMIC_RELAXED, __HIP_MEMORY_SCOPE_AGENT);
}
__device__ __forceinline__ void st_coh_f32(float* p, float v) {
    __hip_atomic_store(p, v, __ATOMIC_RELAXED, __HIP_MEMORY_SCOPE_AGENT);
}
__device__ __forceinline__ unsigned long long ld_coh_u64(const unsigned long long* p) {
    return __hip_atomic_load(p, __ATOMIC_RELAXED, __HIP_MEMORY_SCOPE_AGENT);
}
__device__ __forceinline__ void st_coh_u64(unsigned long long* p, unsigned long long v) {
    __hip_atomic_store(p, v, __ATOMIC_RELAXED, __HIP_MEMORY_SCOPE_AGENT);
}

__device__ __forceinline__ V3 torque_llg(
    float mx, float my, float mz,
    float sux, float suy, float suz,
    float bx, float by, float bz, float cex, float dmg)
{
    const float lx = (sux - 4.0f*mx) * F_IDX2;
    const float ly = (suy - 4.0f*my) * F_IDX2;
    const float lz = (suz - 4.0f*mz) * F_IDX2;
    const float bex = bx + cex*lx;
    const float bey = by + cex*ly;
    const float bez = (bz + cex*lz) + dmg*mz;
    const float ax = my*bez - mz*bey;
    const float ay = mz*bex - mx*bez;
    const float az = mx*bey - my*bex;
    const float cx = my*az - mz*ay;
    const float cy = mz*ax - mx*az;
    const float cz = mx*ay - my*ax;
    // sot = C_SOT * (m x (m x p)), p=(0,1,0)
    const float sx = my*mx;
    const float sy = mz*(-mz) - mx*mx;
    const float sz = my*mz;
    V3 t;
    t.x = F_CLLG*(ax + F_ALPHA*cx) + F_CSOT*sx;
    t.y = F_CLLG*(ay + F_ALPHA*cy) + F_CSOT*sy;
    t.z = F_CLLG*(az + F_ALPHA*cz) + F_CSOT*sz;
    return t;
}

__global__ __launch_bounds__(NTHR, 1) void mm_persist(
    const float* __restrict__ signal, const float* __restrict__ B_ext,
    const float* __restrict__ Msat, const int* __restrict__ src_idx,
    const int* __restrict__ probe_idx, float* __restrict__ out,
    float* __restrict__ ws)
{
    __shared__ float4 tri[3][NTHR];     // [0]=base/m_mid plane, [1],[2]=trials
    __shared__ float  sgl[2*T_STEPS];   // full signal

    const int tid = threadIdx.x;
    const int bid = blockIdx.x;
    const int br = bid >> 3, bc = bid & 7;
    const int r0 = br*16, c0 = bc*16;

    // ws layout: ulong xy[2][NPLANE] | float z[2][NPLANE] | int flags[]
    unsigned long long* xy = (unsigned long long*)ws;
    float* zz = (float*)(xy + 2*NPLANE);
    int* flags = (int*)(zz + 2*NPLANE);

    // ---- fixed per-thread geometry ----
    const int er = tid >> 5, ec = tid & 31;
    const int gr = r0 - 8 + er, gc = c0 - 8 + ec;
    const bool in_grid = ((unsigned)gr < (unsigned)GNX) && ((unsigned)gc < (unsigned)GNX);
    const int grc = min(max(gr, 0), GNX-1), gcc = min(max(gc, 0), GNX-1);
    const int gidx = grc*GNX + gcc;
    const int dd0 = min(min(er, 31-er), min(ec, 31-ec));
    const int dd  = in_grid ? dd0 : -1;   // active@k iff dd>k; ring iff 0<=dd<8

    // neighbor LDS indices, grid-edge clamp baked in
    const int iU = (((gr == 0)     ? er : er-1) << 5) | ec;
    const int iD = (((gr == GNX-1) ? er : er+1) << 5) | ec;
    const int iL = (er << 5) | ((gc == 0)     ? ec : ec-1);
    const int iR = (er << 5) | ((gc == GNX-1) ? ec : ec+1);

    // static per-cell fields in registers
    const float bxr = B_ext[0*NPLANE + gidx];
    const float byr = B_ext[1*NPLANE + gidx];
    const float bzr = B_ext[2*NPLANE + gidx];
    const float ms  = Msat[gidx];
    const float cex = F_2A / ms;
    const float dmg = F_NMU0 * ms;
    const bool isS0 = in_grid && (gr == src_idx[0]) && (gc == src_idx[1]);
    const bool isS1 = in_grid && (gr == src_idx[2]) && (gc == src_idx[3]);
    int pr[4], pc[4];
    #pragma unroll
    for (int j = 0; j < 4; ++j) { pr[j] = probe_idx[2*j]; pc[j] = probe_idx[2*j+1]; }

    // my polled neighbor (threads 0..7), -1 if off-grid
    int my_nb = -1;
    if (tid < 8) {
        const int j  = (tid < 4) ? tid : tid + 1;   // skip center
        const int nr = br + j/3 - 1, nc = bc + (j - (j/3)*3) - 1;
        if (nr >= 0 && nr < NBS && nc >= 0 && nc < NBS) my_nb = nr*NBS + nc;
    }

    // ---- init: m0 = y-hat everywhere; stage signal ----
    if (tid < 2*T_STEPS) sgl[tid] = signal[tid];
    tri[0][tid] = make_float4(0.f, 1.f, 0.f, 0.f);
    float bmx = 0.f, bmy = 1.f, bmz = 0.f;    // own base m
    float kx = 0.f, ky = 0.f, kz = 0.f;       // RK4 accumulator (registers)
    float twx = 0.f, twy = 1.f, twz = 0.f;    // own last trial
    __syncthreads();

    for (int e = 0; e < NEPOCH; ++e) {
        const int cb = e & 1, pb = cb ^ 1;

        if (e > 0) {
            // wait for neighbors to have completed epoch e-1
            if (my_nb >= 0) {
                const int* fp = flags + my_nb*FSTR;
                while (__hip_atomic_load(fp, __ATOMIC_RELAXED,
                                         __HIP_MEMORY_SCOPE_AGENT) < e) {}
            }
            __syncthreads();
            // ring reload: 1x 8B + 1x 4B coherent load per ring cell
            if (dd >= 0 && dd < 8) {
                union { unsigned long long u; float f[2]; } cv;
                cv.u = ld_coh_u64(&xy[(size_t)pb*NPLANE + gidx]);
                const float z = ld_coh_f32(&zz[(size_t)pb*NPLANE + gidx]);
                bmx = cv.f[0]; bmy = cv.f[1]; bmz = z;
                tri[0][tid] = make_float4(bmx, bmy, bmz, 0.f);
            }
        }
        const float sA0 = sgl[4*e+0], sA1 = sgl[4*e+1];
        const float sB0 = sgl[4*e+2], sB1 = sgl[4*e+3];
        kx = 0.f; ky = 0.f; kz = 0.f;   // insurance; consumed sums are
                                        // already reset at their use sites
        __syncthreads();   // ring/base visible

        // ---- 8 RK4 substeps (2 fused time steps), regions 30..16 ----
        #pragma unroll
        for (int k = 0; k < 8; ++k) {
            const int kk = k & 3;
            const float wk = (kk == 1 || kk == 2) ? 2.0f : 1.0f;
            const float cc = (kk == 2) ? 1.0f : 0.5f;
            const float sg0 = (k < 4) ? sA0 : sB0;
            const float sg1 = (k < 4) ? sA1 : sB1;
            const int rs  = (kk == 0) ? 0 : ((kk == 2) ? 2 : 1);
            const int wsb = (kk == 1) ? 2 : 1;

            if (dd > k) {
                const float4 nu = tri[rs][iU];
                const float4 nd = tri[rs][iD];
                const float4 nl = tri[rs][iL];
                const float4 nr = tri[rs][iR];
                float mx, my, mz;
                if (kk == 0) { mx = bmx; my = bmy; mz = bmz; }
                else         { mx = twx; my = twy; mz = twz; }
                const float sux = ((nd.x + nu.x) + nr.x) + nl.x;
                const float suy = ((nd.y + nu.y) + nr.y) + nl.y;
                const float suz = ((nd.z + nu.z) + nr.z) + nl.z;

                float bz = isS0 ? sg0 : bzr;
                bz = isS1 ? sg1 : bz;

                const V3 tq = torque_llg(mx, my, mz, sux, suy, suz,
                                         bxr, byr, bz, cex, dmg);
                // FIX (R5 bug): accumulate only when this sum is consumed
                // before its reset: k=0..3 -> mid-update users (dd>3),
                // k=4..7 -> final users (dd>7).
                if (dd > (k | 3)) {
                    kx += wk*tq.x; ky += wk*tq.y; kz += wk*tq.z;
                }

                if (kk < 3) {
                    twx = bmx + (F_H*tq.x)*cc;
                    twy = bmy + (F_H*tq.y)*cc;
                    twz = bmz + (F_H*tq.z)*cc;
                    tri[wsb][tid] = make_float4(twx, twy, twz, 0.f);
                } else {
                    // mid (k==3) / final (k==7): advance base by H/6 * ka
                    bmx += F_H6*kx; bmy += F_H6*ky; bmz += F_H6*kz;
                    kx = 0.f; ky = 0.f; kz = 0.f;
                    tri[0][tid] = make_float4(bmx, bmy, bmz, 0.f);
                    if (dd >= 8) {   // interior: probes (+publish at k==7)
                        const int tstep = 2*e + (k >> 2);
                        if (k == 7) {
                            union { unsigned long long u; float f[2]; } cv;
                            cv.f[0] = bmx; cv.f[1] = bmy;
                            st_coh_u64(&xy[(size_t)cb*NPLANE + gidx], cv.u);
                            st_coh_f32(&zz[(size_t)cb*NPLANE + gidx], bmz);
                        }
                        #pragma unroll
                        for (int j = 0; j < 4; ++j) {
                            if (gr == pr[j] && gc == pc[j]) {
                                out[tstep*4 + j] = bmz * ms;   // m0_z == 0
                            }
                        }
                    }
                }
            }
            __syncthreads();
        }

        // barrier above drained vmcnt: publish stores are at the coherence
        // point before the flag becomes visible.
        if (tid == 0) {
            __hip_atomic_store(flags + bid*FSTR, e + 1, __ATOMIC_RELAXED,
                               __HIP_MEMORY_SCOPE_AGENT);
        }
    }
}

extern "C" void kernel_launch(void* const* d_in, const int* in_sizes, int n_in,
                              void* d_out, int out_size, void* d_ws, size_t ws_size,
                              hipStream_t stream) {
    const float* sig  = (const float*)d_in[0];
    const float* Bex  = (const float*)d_in[1];
    const float* Ms   = (const float*)d_in[2];
    const int*   srci = (const int*)d_in[3];
    const int*   prbi = (const int*)d_in[4];
    float* out = (float*)d_out;
    float* ws  = (float*)d_ws;

    void* args[] = { (void*)&sig, (void*)&Bex, (void*)&Ms,
                     (void*)&srci, (void*)&prbi, (void*)&out, (void*)&ws };
    hipLaunchCooperativeKernel((const void*)mm_persist, dim3(NBLK), dim3(NTHR),
                               args, 0, stream);
}

// Round 8
// 648.005 us; speedup vs baseline: 6.0040x; 1.1800x over previous
//
#include <hip/hip_runtime.h>

// Micromagnetic LLG + RK4, 128x128 grid, 256 signal steps.
// Exact simplifications (verified R0-R6, absmax ~2e-31):
//  - 100 relaxation steps are a bit-exact no-op => m0 = y-hat, m0_z = 0.
//  - probe value = mz_new * Msat.
//
// R7 = R6 structure spread over ALL 256 CUs.
//  R6 used 64 blocks (64 CUs; 192 idle): ~2.5us/epoch VALU + ~2.9us
//  exchange latency. R7: 256 blocks x 576 threads, 8x8 interior, EXT=24
//  (halo-8, K=2 fused steps, 128 epochs). Per-CU compute drops 4400->1968
//  cell-substeps/epoch; exchange is latency-bound and stays ~constant.
//  All dd-gating is halo/K-derived and carries over verbatim:
//  active@k iff dd>k (regions 22..8), ka-gate dd>(k|3), interior dd>=8.
//
// Everything else proven in R3-R6: sc1 agent-scope per-access coherent
// exchange + relaxed flags, double-buffered planes bound skew to 1 epoch,
// fixed thread<->cell mapping, float4 LDS trial planes (4x ds_read_b128 +
// 1x ds_write_b128 per substep), base m / B_ext / Msat coeffs / RK4
// accumulator in registers. ws 0xAA poison = negative flag => safe spin.

#define GNX 128
#define NPLANE (GNX*GNX)
#define T_STEPS 256
#define NEPOCH 128

constexpr int NBS  = 16;               // 16x16 blocks
constexpr int NBLK = 256;
constexpr int EXT  = 24;               // 8 interior + 2*8 halo
constexpr int NTHR = EXT*EXT;          // 576 = 9 waves
constexpr int FSTR = 32;               // flag stride in ints

constexpr float F_H    = (float)(175950000000.0 * 1e-13);            // GAMMA*DT
constexpr float F_H6   = (float)(175950000000.0 * 1e-13 / 6.0);
constexpr float F_IDX2 = (float)(1.0 / (5e-09 * 5e-09));
constexpr float F_2A   = (float)(2.0 * 1.3e-11);
constexpr float F_NMU0 = (float)(-(4e-07 * 3.14159265358979323846));
constexpr float F_CSOT = 0.001f;
constexpr float F_ALPHA= 0.02f;
constexpr float F_CLLG = (float)(-(1.0 / (1.0 + 0.02*0.02)));

struct V3 { float x, y, z; };

__device__ __forceinline__ float ld_coh_f32(const float* p) {
    return __hip_atomic_load(p, __ATOMIC_RELAXED, __HIP_MEMORY_SCOPE_AGENT);
}
__device__ __forceinline__ void st_coh_f32(float* p, float v) {
    __hip_atomic_store(p, v, __ATOMIC_RELAXED, __HIP_MEMORY_SCOPE_AGENT);
}
__device__ __forceinline__ unsigned long long ld_coh_u64(const unsigned long long* p) {
    return __hip_atomic_load(p, __ATOMIC_RELAXED, __HIP_MEMORY_SCOPE_AGENT);
}
__device__ __forceinline__ void st_coh_u64(unsigned long long* p, unsigned long long v) {
    __hip_atomic_store(p, v, __ATOMIC_RELAXED, __HIP_MEMORY_SCOPE_AGENT);
}

__device__ __forceinline__ V3 torque_llg(
    float mx, float my, float mz,
    float sux, float suy, float suz,
    float bx, float by, float bz, float cex, float dmg)
{
    const float lx = (sux - 4.0f*mx) * F_IDX2;
    const float ly = (suy - 4.0f*my) * F_IDX2;
    const float lz = (suz - 4.0f*mz) * F_IDX2;
    const float bex = bx + cex*lx;
    const float bey = by + cex*ly;
    const float bez = (bz + cex*lz) + dmg*mz;
    const float ax = my*bez - mz*bey;
    const float ay = mz*bex - mx*bez;
    const float az = mx*bey - my*bex;
    const float cx = my*az - mz*ay;
    const float cy = mz*ax - mx*az;
    const float cz = mx*ay - my*ax;
    // sot = C_SOT * (m x (m x p)), p=(0,1,0)
    const float sx = my*mx;
    const float sy = mz*(-mz) - mx*mx;
    const float sz = my*mz;
    V3 t;
    t.x = F_CLLG*(ax + F_ALPHA*cx) + F_CSOT*sx;
    t.y = F_CLLG*(ay + F_ALPHA*cy) + F_CSOT*sy;
    t.z = F_CLLG*(az + F_ALPHA*cz) + F_CSOT*sz;
    return t;
}

__global__ __launch_bounds__(NTHR, 1) void mm_persist(
    const float* __restrict__ signal, const float* __restrict__ B_ext,
    const float* __restrict__ Msat, const int* __restrict__ src_idx,
    const int* __restrict__ probe_idx, float* __restrict__ out,
    float* __restrict__ ws)
{
    __shared__ float4 tri[3][NTHR];     // [0]=base/m_mid plane, [1],[2]=trials
    __shared__ float  sgl[2*T_STEPS];   // full signal

    const int tid = threadIdx.x;
    const int bid = blockIdx.x;
    const int br = bid >> 4, bc = bid & 15;
    const int r0 = br*8, c0 = bc*8;

    // ws layout: ulong xy[2][NPLANE] | float z[2][NPLANE] | int flags[]
    unsigned long long* xy = (unsigned long long*)ws;
    float* zz = (float*)(xy + 2*NPLANE);
    int* flags = (int*)(zz + 2*NPLANE);

    // ---- fixed per-thread geometry ----
    const int er = tid / EXT, ec = tid - (tid/EXT)*EXT;
    const int gr = r0 - 8 + er, gc = c0 - 8 + ec;
    const bool in_grid = ((unsigned)gr < (unsigned)GNX) && ((unsigned)gc < (unsigned)GNX);
    const int grc = min(max(gr, 0), GNX-1), gcc = min(max(gc, 0), GNX-1);
    const int gidx = grc*GNX + gcc;
    const int dd0 = min(min(er, EXT-1-er), min(ec, EXT-1-ec));
    const int dd  = in_grid ? dd0 : -1;   // active@k iff dd>k; ring iff 0<=dd<8

    // neighbor LDS indices, grid-edge clamp baked in
    const int iU = (((gr == 0)     ? er : er-1) * EXT) + ec;
    const int iD = (((gr == GNX-1) ? er : er+1) * EXT) + ec;
    const int iL = (er * EXT) + ((gc == 0)     ? ec : ec-1);
    const int iR = (er * EXT) + ((gc == GNX-1) ? ec : ec+1);

    // static per-cell fields in registers
    const float bxr = B_ext[0*NPLANE + gidx];
    const float byr = B_ext[1*NPLANE + gidx];
    const float bzr = B_ext[2*NPLANE + gidx];
    const float ms  = Msat[gidx];
    const float cex = F_2A / ms;
    const float dmg = F_NMU0 * ms;
    const bool isS0 = in_grid && (gr == src_idx[0]) && (gc == src_idx[1]);
    const bool isS1 = in_grid && (gr == src_idx[2]) && (gc == src_idx[3]);
    int pr[4], pc[4];
    #pragma unroll
    for (int j = 0; j < 4; ++j) { pr[j] = probe_idx[2*j]; pc[j] = probe_idx[2*j+1]; }

    // my polled neighbor (threads 0..7), -1 if off-grid
    int my_nb = -1;
    if (tid < 8) {
        const int j  = (tid < 4) ? tid : tid + 1;   // skip center (3x3 - self)
        const int nr = br + j/3 - 1, nc = bc + (j - (j/3)*3) - 1;
        if (nr >= 0 && nr < NBS && nc >= 0 && nc < NBS) my_nb = nr*NBS + nc;
    }

    // ---- init: m0 = y-hat everywhere; stage signal ----
    if (tid < 2*T_STEPS) sgl[tid] = signal[tid];
    tri[0][tid] = make_float4(0.f, 1.f, 0.f, 0.f);
    float bmx = 0.f, bmy = 1.f, bmz = 0.f;    // own base m
    float kx = 0.f, ky = 0.f, kz = 0.f;       // RK4 accumulator (registers)
    float twx = 0.f, twy = 1.f, twz = 0.f;    // own last trial
    __syncthreads();

    for (int e = 0; e < NEPOCH; ++e) {
        const int cb = e & 1, pb = cb ^ 1;

        if (e > 0) {
            // wait for neighbors to have completed epoch e-1
            if (my_nb >= 0) {
                const int* fp = flags + my_nb*FSTR;
                while (__hip_atomic_load(fp, __ATOMIC_RELAXED,
                                         __HIP_MEMORY_SCOPE_AGENT) < e) {}
            }
            __syncthreads();
            // ring reload: 1x 8B + 1x 4B coherent load per ring cell
            if (dd >= 0 && dd < 8) {
                union { unsigned long long u; float f[2]; } cv;
                cv.u = ld_coh_u64(&xy[(size_t)pb*NPLANE + gidx]);
                const float z = ld_coh_f32(&zz[(size_t)pb*NPLANE + gidx]);
                bmx = cv.f[0]; bmy = cv.f[1]; bmz = z;
                tri[0][tid] = make_float4(bmx, bmy, bmz, 0.f);
            }
        }
        const float sA0 = sgl[4*e+0], sA1 = sgl[4*e+1];
        const float sB0 = sgl[4*e+2], sB1 = sgl[4*e+3];
        kx = 0.f; ky = 0.f; kz = 0.f;   // insurance; consumed sums are
                                        // already reset at their use sites
        __syncthreads();   // ring/base visible

        // ---- 8 RK4 substeps (2 fused time steps), regions 22..8 ----
        #pragma unroll
        for (int k = 0; k < 8; ++k) {
            const int kk = k & 3;
            const float wk = (kk == 1 || kk == 2) ? 2.0f : 1.0f;
            const float cc = (kk == 2) ? 1.0f : 0.5f;
            const float sg0 = (k < 4) ? sA0 : sB0;
            const float sg1 = (k < 4) ? sA1 : sB1;
            const int rs  = (kk == 0) ? 0 : ((kk == 2) ? 2 : 1);
            const int wsb = (kk == 1) ? 2 : 1;

            if (dd > k) {
                const float4 nu = tri[rs][iU];
                const float4 nd = tri[rs][iD];
                const float4 nl = tri[rs][iL];
                const float4 nr = tri[rs][iR];
                float mx, my, mz;
                if (kk == 0) { mx = bmx; my = bmy; mz = bmz; }
                else         { mx = twx; my = twy; mz = twz; }
                const float sux = ((nd.x + nu.x) + nr.x) + nl.x;
                const float suy = ((nd.y + nu.y) + nr.y) + nl.y;
                const float suz = ((nd.z + nu.z) + nr.z) + nl.z;

                float bz = isS0 ? sg0 : bzr;
                bz = isS1 ? sg1 : bz;

                const V3 tq = torque_llg(mx, my, mz, sux, suy, suz,
                                         bxr, byr, bz, cex, dmg);
                // accumulate only when this sum is consumed before its
                // reset: k=0..3 -> mid-update users (dd>3), k=4..7 ->
                // final users (dd>7).  (R5-bug fix, verified R6)
                if (dd > (k | 3)) {
                    kx += wk*tq.x; ky += wk*tq.y; kz += wk*tq.z;
                }

                if (kk < 3) {
                    twx = bmx + (F_H*tq.x)*cc;
                    twy = bmy + (F_H*tq.y)*cc;
                    twz = bmz + (F_H*tq.z)*cc;
                    tri[wsb][tid] = make_float4(twx, twy, twz, 0.f);
                } else {
                    // mid (k==3) / final (k==7): advance base by H/6 * ka
                    bmx += F_H6*kx; bmy += F_H6*ky; bmz += F_H6*kz;
                    kx = 0.f; ky = 0.f; kz = 0.f;
                    tri[0][tid] = make_float4(bmx, bmy, bmz, 0.f);
                    if (dd >= 8) {   // interior: probes (+publish at k==7)
                        const int tstep = 2*e + (k >> 2);
                        if (k == 7) {
                            union { unsigned long long u; float f[2]; } cv;
                            cv.f[0] = bmx; cv.f[1] = bmy;
                            st_coh_u64(&xy[(size_t)cb*NPLANE + gidx], cv.u);
                            st_coh_f32(&zz[(size_t)cb*NPLANE + gidx], bmz);
                        }
                        #pragma unroll
                        for (int j = 0; j < 4; ++j) {
                            if (gr == pr[j] && gc == pc[j]) {
                                out[tstep*4 + j] = bmz * ms;   // m0_z == 0
                            }
                        }
                    }
                }
            }
            __syncthreads();
        }

        // barrier above drained vmcnt: publish stores are at the coherence
        // point before the flag becomes visible.
        if (tid == 0) {
            __hip_atomic_store(flags + bid*FSTR, e + 1, __ATOMIC_RELAXED,
                               __HIP_MEMORY_SCOPE_AGENT);
        }
    }
}

extern "C" void kernel_launch(void* const* d_in, const int* in_sizes, int n_in,
                              void* d_out, int out_size, void* d_ws, size_t ws_size,
                              hipStream_t stream) {
    const float* sig  = (const float*)d_in[0];
    const float* Bex  = (const float*)d_in[1];
    const float* Ms   = (const float*)d_in[2];
    const int*   srci = (const int*)d_in[3];
    const int*   prbi = (const int*)d_in[4];
    float* out = (float*)d_out;
    float* ws  = (float*)d_ws;

    void* args[] = { (void*)&sig, (void*)&Bex, (void*)&Ms,
                     (void*)&srci, (void*)&prbi, (void*)&out, (void*)&ws };
    hipLaunchCooperativeKernel((const void*)mm_persist, dim3(NBLK), dim3(NTHR),
                               args, 0, stream);
}

// Round 9
// 636.313 us; speedup vs baseline: 6.1143x; 1.0184x over previous
//
#include <hip/hip_runtime.h>

// Micromagnetic LLG + RK4, 128x128 grid, 256 signal steps.
// Exact simplifications (verified R0-R7, absmax ~2e-31):
//  - 100 relaxation steps are a bit-exact no-op => m0 = y-hat, m0_z = 0.
//  - probe value = mz_new * Msat.
//
// R8 = R7 + K=3 fusion + Manhattan-diamond gating.
//  R7 measured: 1.4us/epoch VALU + ~3.2us/epoch exchange-latency chain
//  (latency-bound, 1.9% HBM BW). Exchange cost is fixed per epoch =>
//  amortize: 3 steps per epoch (halo 12, EXT=32 = 1024 thr, interior 8x8,
//  256 blocks) -> 86 epochs (85 full + 1 tail step) instead of 128.
//  The 5-point stencil dependency is a Manhattan DIAMOND, not a square:
//  activity gate D <= 11-k (D = Manhattan distance to interior square),
//  ka-accumulate gate D <= 11-(k|3) (sum consumed at its mid/final
//  update; generalizes R6's dd>(k|3) proof), advance at kk==3 iff
//  active, publish/probes iff D==0. Ring reload: 1 <= D <= 12.
//  Diamond gating cuts ~21% of corner redundancy and 25% of ring loads.
//
// Exchange machinery proven R3-R7: sc1 agent-scope per-access coherent
// ops + relaxed agent flags; double-buffered planes bound neighbor skew
// to 1 epoch; ws 0xAA poison = negative flag => safe spin; __syncthreads
// drains vmcnt so band stores reach the coherence point before the flag.

#define GNX 128
#define NPLANE (GNX*GNX)
#define T_STEPS 256

constexpr int NBS   = 16;              // 16x16 blocks of 8x8 interior
constexpr int NBLK  = 256;
constexpr int EXT   = 32;              // 8 + 2*12 halo
constexpr int NTHR  = 1024;
constexpr int HALO  = 12;
constexpr int NFULL = 85;              // 85 epochs x 3 steps + 1 tail step
constexpr int FSTR  = 32;              // flag stride in ints

constexpr float F_H    = (float)(175950000000.0 * 1e-13);            // GAMMA*DT
constexpr float F_H6   = (float)(175950000000.0 * 1e-13 / 6.0);
constexpr float F_IDX2 = (float)(1.0 / (5e-09 * 5e-09));
constexpr float F_2A   = (float)(2.0 * 1.3e-11);
constexpr float F_NMU0 = (float)(-(4e-07 * 3.14159265358979323846));
constexpr float F_CSOT = 0.001f;
constexpr float F_ALPHA= 0.02f;
constexpr float F_CLLG = (float)(-(1.0 / (1.0 + 0.02*0.02)));

struct V3 { float x, y, z; };

__device__ __forceinline__ float ld_coh_f32(const float* p) {
    return __hip_atomic_load(p, __ATOMIC_RELAXED, __HIP_MEMORY_SCOPE_AGENT);
}
__device__ __forceinline__ void st_coh_f32(float* p, float v) {
    __hip_atomic_store(p, v, __ATOMIC_RELAXED, __HIP_MEMORY_SCOPE_AGENT);
}
__device__ __forceinline__ unsigned long long ld_coh_u64(const unsigned long long* p) {
    return __hip_atomic_load(p, __ATOMIC_RELAXED, __HIP_MEMORY_SCOPE_AGENT);
}
__device__ __forceinline__ void st_coh_u64(unsigned long long* p, unsigned long long v) {
    __hip_atomic_store(p, v, __ATOMIC_RELAXED, __HIP_MEMORY_SCOPE_AGENT);
}

__device__ __forceinline__ V3 torque_llg(
    float mx, float my, float mz,
    float sux, float suy, float suz,
    float bx, float by, float bz, float cex, float dmg)
{
    const float lx = (sux - 4.0f*mx) * F_IDX2;
    const float ly = (suy - 4.0f*my) * F_IDX2;
    const float lz = (suz - 4.0f*mz) * F_IDX2;
    const float bex = bx + cex*lx;
    const float bey = by + cex*ly;
    const float bez = (bz + cex*lz) + dmg*mz;
    const float ax = my*bez - mz*bey;
    const float ay = mz*bex - mx*bez;
    const float az = mx*bey - my*bex;
    const float cx = my*az - mz*ay;
    const float cy = mz*ax - mx*az;
    const float cz = mx*ay - my*ax;
    // sot = C_SOT * (m x (m x p)), p=(0,1,0)
    const float sx = my*mx;
    const float sy = mz*(-mz) - mx*mx;
    const float sz = my*mz;
    V3 t;
    t.x = F_CLLG*(ax + F_ALPHA*cx) + F_CSOT*sx;
    t.y = F_CLLG*(ay + F_ALPHA*cy) + F_CSOT*sy;
    t.z = F_CLLG*(az + F_ALPHA*cz) + F_CSOT*sz;
    return t;
}

__global__ __launch_bounds__(NTHR, 1) void mm_persist(
    const float* __restrict__ signal, const float* __restrict__ B_ext,
    const float* __restrict__ Msat, const int* __restrict__ src_idx,
    const int* __restrict__ probe_idx, float* __restrict__ out,
    float* __restrict__ ws)
{
    __shared__ float4 tri[3][NTHR];       // [0]=base plane, [1],[2]=trials
    __shared__ float  sgl[2*T_STEPS + 8]; // signal (+pad for tail reads)

    const int tid = threadIdx.x;
    const int bid = blockIdx.x;
    const int br = bid >> 4, bc = bid & 15;
    const int r0 = br*8, c0 = bc*8;

    // ws layout: ulong xy[2][NPLANE] | float z[2][NPLANE] | int flags[]
    unsigned long long* xy = (unsigned long long*)ws;
    float* zz = (float*)(xy + 2*NPLANE);
    int* flags = (int*)(zz + 2*NPLANE);

    // ---- fixed per-thread geometry ----
    const int er = tid >> 5, ec = tid & 31;
    const int gr = r0 - HALO + er, gc = c0 - HALO + ec;
    const bool in_grid = ((unsigned)gr < (unsigned)GNX) && ((unsigned)gc < (unsigned)GNX);
    const int grc = min(max(gr, 0), GNX-1), gcc = min(max(gc, 0), GNX-1);
    const int gidx = grc*GNX + gcc;
    // Manhattan distance to the 8x8 interior square [HALO, HALO+8)
    const int drr = max(max(HALO - er, er - (HALO+7)), 0);
    const int dcc = max(max(HALO - ec, ec - (HALO+7)), 0);
    const int D = in_grid ? (drr + dcc) : 99;

    // neighbor LDS indices, grid-edge clamp baked in
    const int iU = (((gr == 0)     ? er : er-1) << 5) | ec;
    const int iD = (((gr == GNX-1) ? er : er+1) << 5) | ec;
    const int iL = (er << 5) | ((gc == 0)     ? ec : ec-1);
    const int iR = (er << 5) | ((gc == GNX-1) ? ec : ec+1);

    // static per-cell fields in registers
    const float bxr = B_ext[0*NPLANE + gidx];
    const float byr = B_ext[1*NPLANE + gidx];
    const float bzr = B_ext[2*NPLANE + gidx];
    const float ms  = Msat[gidx];
    const float cex = F_2A / ms;
    const float dmg = F_NMU0 * ms;
    const bool isS0 = in_grid && (gr == src_idx[0]) && (gc == src_idx[1]);
    const bool isS1 = in_grid && (gr == src_idx[2]) && (gc == src_idx[3]);
    int pr[4], pc[4];
    #pragma unroll
    for (int j = 0; j < 4; ++j) { pr[j] = probe_idx[2*j]; pc[j] = probe_idx[2*j+1]; }

    // my polled neighbor (threads 0..7), -1 if off-grid
    int my_nb = -1;
    if (tid < 8) {
        const int j  = (tid < 4) ? tid : tid + 1;   // skip center (3x3 - self)
        const int nr = br + j/3 - 1, nc = bc + (j - (j/3)*3) - 1;
        if (nr >= 0 && nr < NBS && nc >= 0 && nc < NBS) my_nb = nr*NBS + nc;
    }

    // ---- init: m0 = y-hat everywhere; stage signal ----
    if (tid < 2*T_STEPS) sgl[tid] = signal[tid];
    tri[0][tid] = make_float4(0.f, 1.f, 0.f, 0.f);
    float bmx = 0.f, bmy = 1.f, bmz = 0.f;    // own base m
    float kx = 0.f, ky = 0.f, kz = 0.f;       // RK4 accumulator (registers)
    float twx = 0.f, twy = 1.f, twz = 0.f;    // own last trial
    __syncthreads();

    for (int e = 0; e <= NFULL; ++e) {
        const int cb = e & 1, pb = cb ^ 1;

        if (e > 0) {
            // wait for neighbors to have completed epoch e-1
            if (my_nb >= 0) {
                const int* fp = flags + my_nb*FSTR;
                while (__hip_atomic_load(fp, __ATOMIC_RELAXED,
                                         __HIP_MEMORY_SCOPE_AGENT) < e) {}
            }
            __syncthreads();
            // ring reload: only diamond-relevant cells (1 <= D <= 12)
            if (D >= 1 && D <= 12) {
                union { unsigned long long u; float f[2]; } cv;
                cv.u = ld_coh_u64(&xy[(size_t)pb*NPLANE + gidx]);
                const float z = ld_coh_f32(&zz[(size_t)pb*NPLANE + gidx]);
                bmx = cv.f[0]; bmy = cv.f[1]; bmz = z;
                tri[0][tid] = make_float4(bmx, bmy, bmz, 0.f);
            }
        }
        // signal pairs for the (up to) 3 steps of this epoch
        const float spA0 = sgl[6*e+0], spA1 = sgl[6*e+1];
        const float spB0 = sgl[6*e+2], spB1 = sgl[6*e+3];
        const float spC0 = sgl[6*e+4], spC1 = sgl[6*e+5];  // pad-safe; tail unused
        kx = 0.f; ky = 0.f; kz = 0.f;   // insurance; gated sums reset at use
        __syncthreads();   // ring/base visible

        auto substep = [&](int k) {
            const int kk = k & 3;
            const float wk = (kk == 1 || kk == 2) ? 2.0f : 1.0f;
            const float cc = (kk == 2) ? 1.0f : 0.5f;
            const float sg0 = (k < 4) ? spA0 : ((k < 8) ? spB0 : spC0);
            const float sg1 = (k < 4) ? spA1 : ((k < 8) ? spB1 : spC1);
            const int rs  = (kk == 0) ? 0 : ((kk == 2) ? 2 : 1);
            const int wsb = (kk == 1) ? 2 : 1;

            if (D <= 11 - k) {            // diamond activity gate
                const float4 nu = tri[rs][iU];
                const float4 nd = tri[rs][iD];
                const float4 nl = tri[rs][iL];
                const float4 nr = tri[rs][iR];
                float mx, my, mz;
                if (kk == 0) { mx = bmx; my = bmy; mz = bmz; }
                else         { mx = twx; my = twy; mz = twz; }
                const float sux = ((nd.x + nu.x) + nr.x) + nl.x;
                const float suy = ((nd.y + nu.y) + nr.y) + nl.y;
                const float suz = ((nd.z + nu.z) + nr.z) + nl.z;

                float bz = isS0 ? sg0 : bzr;
                bz = isS1 ? sg1 : bz;

                const V3 tq = torque_llg(mx, my, mz, sux, suy, suz,
                                         bxr, byr, bz, cex, dmg);
                // accumulate only if this sum is consumed at its mid/final
                // update (k|3), i.e. cell still active there. (R6 proof,
                // Manhattan form)
                if (D <= 11 - (k | 3)) {
                    kx += wk*tq.x; ky += wk*tq.y; kz += wk*tq.z;
                }

                if (kk < 3) {
                    twx = bmx + (F_H*tq.x)*cc;
                    twy = bmy + (F_H*tq.y)*cc;
                    twz = bmz + (F_H*tq.z)*cc;
                    tri[wsb][tid] = make_float4(twx, twy, twz, 0.f);
                } else {
                    // mid/final: advance base by H/6 * ka (active => consumer)
                    bmx += F_H6*kx; bmy += F_H6*ky; bmz += F_H6*kz;
                    kx = 0.f; ky = 0.f; kz = 0.f;
                    tri[0][tid] = make_float4(bmx, bmy, bmz, 0.f);
                    if (D == 0) {        // interior: publish at k==11, probes
                        if (k == 11) {
                            union { unsigned long long u; float f[2]; } cv;
                            cv.f[0] = bmx; cv.f[1] = bmy;
                            st_coh_u64(&xy[(size_t)cb*NPLANE + gidx], cv.u);
                            st_coh_f32(&zz[(size_t)cb*NPLANE + gidx], bmz);
                        }
                        const int tstep = 3*e + (k >> 2);
                        #pragma unroll
                        for (int j = 0; j < 4; ++j) {
                            if (gr == pr[j] && gc == pc[j]) {
                                out[tstep*4 + j] = bmz * ms;   // m0_z == 0
                            }
                        }
                    }
                }
            }
        };

        if (e < NFULL) {
            #pragma unroll
            for (int k = 0; k < 12; ++k) { substep(k); __syncthreads(); }
            // barrier drained vmcnt: publish stores are at the coherence
            // point before the flag becomes visible.
            if (tid == 0) {
                __hip_atomic_store(flags + bid*FSTR, e + 1, __ATOMIC_RELAXED,
                                   __HIP_MEMORY_SCOPE_AGENT);
            }
        } else {
            // tail: one final step (t=255), no publish needed
            #pragma unroll
            for (int k = 0; k < 4; ++k) { substep(k); __syncthreads(); }
        }
    }
}

extern "C" void kernel_launch(void* const* d_in, const int* in_sizes, int n_in,
                              void* d_out, int out_size, void* d_ws, size_t ws_size,
                              hipStream_t stream) {
    const float* sig  = (const float*)d_in[0];
    const float* Bex  = (const float*)d_in[1];
    const float* Ms   = (const float*)d_in[2];
    const int*   srci = (const int*)d_in[3];
    const int*   prbi = (const int*)d_in[4];
    float* out = (float*)d_out;
    float* ws  = (float*)d_ws;

    void* args[] = { (void*)&sig, (void*)&Bex, (void*)&Ms,
                     (void*)&srci, (void*)&prbi, (void*)&out, (void*)&ws };
    hipLaunchCooperativeKernel((const void*)mm_persist, dim3(NBLK), dim3(NTHR),
                               args, 0, stream);
}

// Round 10
// 631.125 us; speedup vs baseline: 6.1646x; 1.0082x over previous
//
#include <hip/hip_runtime.h>

// Micromagnetic LLG + RK4, 128x128 grid, 256 signal steps.
// Exact simplifications (verified R0-R8, absmax ~2e-31):
//  - 100 relaxation steps are a bit-exact no-op => m0 = y-hat, m0_z = 0.
//  - probe value = mz_new * Msat.
//
// R9 = R7 geometry (K=2, halo-8, EXT=24, 576thr, 128 epochs; VALU
// 1.4us/epoch — cheapest measured) + R8's Manhattan-diamond gating
// (instantiated for K=2) + PRIVATE PER-PAIR INBOX FLAGS.
//  R8 diagnosis: shared flag lines are polled by ~8 remote reader blocks
//  each, continuously, across XCDs -> serialization at the coherence
//  point inflates detect latency (FETCH scales with wait time, not
//  epoch count: 60->54MB for 128->86 epochs). Fix: writer stores its
//  epoch into the READER's private slot inbox[reader][7-tid] (partner
//  symmetry: offset (dr,dc) -> (-dr,-dc) maps enum tid -> 7-tid);
//  reader polls its own inbox[bid][tid]. Each line: 1 one-shot remote
//  writer + 8 local same-wave readers (1 coalesced poll transaction).
//
// Diamond algebra for K=2/halo-8 (derived from R8's verified K=3 form):
//  active@k iff D <= 7-k; ka-accumulate iff D <= 7-(k|3); mid/final
//  advance at kk==3 iff active; publish/probes iff D==0; ring 1<=D<=8.
// Exchange machinery proven R3-R8: sc1 agent-scope per-access coherent
// ops + relaxed flags; double-buffered planes bound skew to 1 epoch;
// ws 0xAA poison = negative flag => safe spin; __syncthreads drains
// vmcnt so publish stores reach the coherence point before flags.

#define GNX 128
#define NPLANE (GNX*GNX)
#define T_STEPS 256
#define NEPOCH 128

constexpr int NBS   = 16;              // 16x16 blocks of 8x8 interior
constexpr int NBLK  = 256;
constexpr int HALO  = 8;
constexpr int EXT   = 24;              // 8 + 2*8
constexpr int NTHR  = EXT*EXT;         // 576 = 9 waves
constexpr int FSTR  = 32;              // inbox stride per block (ints)

constexpr float F_H    = (float)(175950000000.0 * 1e-13);            // GAMMA*DT
constexpr float F_H6   = (float)(175950000000.0 * 1e-13 / 6.0);
constexpr float F_IDX2 = (float)(1.0 / (5e-09 * 5e-09));
constexpr float F_2A   = (float)(2.0 * 1.3e-11);
constexpr float F_NMU0 = (float)(-(4e-07 * 3.14159265358979323846));
constexpr float F_CSOT = 0.001f;
constexpr float F_ALPHA= 0.02f;
constexpr float F_CLLG = (float)(-(1.0 / (1.0 + 0.02*0.02)));

struct V3 { float x, y, z; };

__device__ __forceinline__ float ld_coh_f32(const float* p) {
    return __hip_atomic_load(p, __ATOMIC_RELAXED, __HIP_MEMORY_SCOPE_AGENT);
}
__device__ __forceinline__ void st_coh_f32(float* p, float v) {
    __hip_atomic_store(p, v, __ATOMIC_RELAXED, __HIP_MEMORY_SCOPE_AGENT);
}
__device__ __forceinline__ unsigned long long ld_coh_u64(const unsigned long long* p) {
    return __hip_atomic_load(p, __ATOMIC_RELAXED, __HIP_MEMORY_SCOPE_AGENT);
}
__device__ __forceinline__ void st_coh_u64(unsigned long long* p, unsigned long long v) {
    __hip_atomic_store(p, v, __ATOMIC_RELAXED, __HIP_MEMORY_SCOPE_AGENT);
}

__device__ __forceinline__ V3 torque_llg(
    float mx, float my, float mz,
    float sux, float suy, float suz,
    float bx, float by, float bz, float cex, float dmg)
{
    const float lx = (sux - 4.0f*mx) * F_IDX2;
    const float ly = (suy - 4.0f*my) * F_IDX2;
    const float lz = (suz - 4.0f*mz) * F_IDX2;
    const float bex = bx + cex*lx;
    const float bey = by + cex*ly;
    const float bez = (bz + cex*lz) + dmg*mz;
    const float ax = my*bez - mz*bey;
    const float ay = mz*bex - mx*bez;
    const float az = mx*bey - my*bex;
    const float cx = my*az - mz*ay;
    const float cy = mz*ax - mx*az;
    const float cz = mx*ay - my*ax;
    // sot = C_SOT * (m x (m x p)), p=(0,1,0)
    const float sx = my*mx;
    const float sy = mz*(-mz) - mx*mx;
    const float sz = my*mz;
    V3 t;
    t.x = F_CLLG*(ax + F_ALPHA*cx) + F_CSOT*sx;
    t.y = F_CLLG*(ay + F_ALPHA*cy) + F_CSOT*sy;
    t.z = F_CLLG*(az + F_ALPHA*cz) + F_CSOT*sz;
    return t;
}

__global__ __launch_bounds__(NTHR, 1) void mm_persist(
    const float* __restrict__ signal, const float* __restrict__ B_ext,
    const float* __restrict__ Msat, const int* __restrict__ src_idx,
    const int* __restrict__ probe_idx, float* __restrict__ out,
    float* __restrict__ ws)
{
    __shared__ float4 tri[3][NTHR];     // [0]=base/m_mid plane, [1],[2]=trials
    __shared__ float  sgl[2*T_STEPS];   // full signal

    const int tid = threadIdx.x;
    const int bid = blockIdx.x;
    const int br = bid >> 4, bc = bid & 15;
    const int r0 = br*8, c0 = bc*8;

    // ws layout: ulong xy[2][NPLANE] | float z[2][NPLANE] | int inbox[]
    unsigned long long* xy = (unsigned long long*)ws;
    float* zz = (float*)(xy + 2*NPLANE);
    int* inbox = (int*)(zz + 2*NPLANE);

    // ---- fixed per-thread geometry ----
    const int er = tid / EXT, ec = tid - (tid/EXT)*EXT;
    const int gr = r0 - HALO + er, gc = c0 - HALO + ec;
    const bool in_grid = ((unsigned)gr < (unsigned)GNX) && ((unsigned)gc < (unsigned)GNX);
    const int grc = min(max(gr, 0), GNX-1), gcc = min(max(gc, 0), GNX-1);
    const int gidx = grc*GNX + gcc;
    // Manhattan distance to the 8x8 interior square [HALO, HALO+8)
    const int drr = max(max(HALO - er, er - (HALO+7)), 0);
    const int dcc = max(max(HALO - ec, ec - (HALO+7)), 0);
    const int D = in_grid ? (drr + dcc) : 99;

    // neighbor LDS indices, grid-edge clamp baked in
    const int iU = (((gr == 0)     ? er : er-1) * EXT) + ec;
    const int iD = (((gr == GNX-1) ? er : er+1) * EXT) + ec;
    const int iL = (er * EXT) + ((gc == 0)     ? ec : ec-1);
    const int iR = (er * EXT) + ((gc == GNX-1) ? ec : ec+1);

    // static per-cell fields in registers
    const float bxr = B_ext[0*NPLANE + gidx];
    const float byr = B_ext[1*NPLANE + gidx];
    const float bzr = B_ext[2*NPLANE + gidx];
    const float ms  = Msat[gidx];
    const float cex = F_2A / ms;
    const float dmg = F_NMU0 * ms;
    const bool isS0 = in_grid && (gr == src_idx[0]) && (gc == src_idx[1]);
    const bool isS1 = in_grid && (gr == src_idx[2]) && (gc == src_idx[3]);
    int pr[4], pc[4];
    #pragma unroll
    for (int j = 0; j < 4; ++j) { pr[j] = probe_idx[2*j]; pc[j] = probe_idx[2*j+1]; }

    // my polled neighbor (threads 0..7), -1 if off-grid.
    // enum: j=(tid<4)?tid:tid+1; offset (j/3-1, j%3-1). Partner index
    // symmetry: the writer's tid maps to reader slot (7 - tid).
    int my_nb = -1;
    if (tid < 8) {
        const int j  = (tid < 4) ? tid : tid + 1;
        const int nr = br + j/3 - 1, nc = bc + (j - (j/3)*3) - 1;
        if (nr >= 0 && nr < NBS && nc >= 0 && nc < NBS) my_nb = nr*NBS + nc;
    }

    // ---- init: m0 = y-hat everywhere; stage signal ----
    if (tid < 2*T_STEPS) sgl[tid] = signal[tid];
    tri[0][tid] = make_float4(0.f, 1.f, 0.f, 0.f);
    float bmx = 0.f, bmy = 1.f, bmz = 0.f;    // own base m
    float kx = 0.f, ky = 0.f, kz = 0.f;       // RK4 accumulator (registers)
    float twx = 0.f, twy = 1.f, twz = 0.f;    // own last trial
    __syncthreads();

    for (int e = 0; e < NEPOCH; ++e) {
        const int cb = e & 1, pb = cb ^ 1;

        if (e > 0) {
            // wait: poll MY private slot for each neighbor direction
            if (my_nb >= 0) {
                const int* fp = inbox + bid*FSTR + tid;
                while (__hip_atomic_load(fp, __ATOMIC_RELAXED,
                                         __HIP_MEMORY_SCOPE_AGENT) < e) {}
            }
            __syncthreads();
            // ring reload: diamond-relevant cells only (1 <= D <= 8)
            if (D >= 1 && D <= 8) {
                union { unsigned long long u; float f[2]; } cv;
                cv.u = ld_coh_u64(&xy[(size_t)pb*NPLANE + gidx]);
                const float z = ld_coh_f32(&zz[(size_t)pb*NPLANE + gidx]);
                bmx = cv.f[0]; bmy = cv.f[1]; bmz = z;
                tri[0][tid] = make_float4(bmx, bmy, bmz, 0.f);
            }
        }
        const float sA0 = sgl[4*e+0], sA1 = sgl[4*e+1];
        const float sB0 = sgl[4*e+2], sB1 = sgl[4*e+3];
        kx = 0.f; ky = 0.f; kz = 0.f;   // insurance; gated sums reset at use
        __syncthreads();   // ring/base visible

        // ---- 8 RK4 substeps (2 fused steps), diamond regions D<=7..0 ----
        #pragma unroll
        for (int k = 0; k < 8; ++k) {
            const int kk = k & 3;
            const float wk = (kk == 1 || kk == 2) ? 2.0f : 1.0f;
            const float cc = (kk == 2) ? 1.0f : 0.5f;
            const float sg0 = (k < 4) ? sA0 : sB0;
            const float sg1 = (k < 4) ? sA1 : sB1;
            const int rs  = (kk == 0) ? 0 : ((kk == 2) ? 2 : 1);
            const int wsb = (kk == 1) ? 2 : 1;

            if (D <= 7 - k) {             // diamond activity gate
                const float4 nu = tri[rs][iU];
                const float4 nd = tri[rs][iD];
                const float4 nl = tri[rs][iL];
                const float4 nr = tri[rs][iR];
                float mx, my, mz;
                if (kk == 0) { mx = bmx; my = bmy; mz = bmz; }
                else         { mx = twx; my = twy; mz = twz; }
                const float sux = ((nd.x + nu.x) + nr.x) + nl.x;
                const float suy = ((nd.y + nu.y) + nr.y) + nl.y;
                const float suz = ((nd.z + nu.z) + nr.z) + nl.z;

                float bz = isS0 ? sg0 : bzr;
                bz = isS1 ? sg1 : bz;

                const V3 tq = torque_llg(mx, my, mz, sux, suy, suz,
                                         bxr, byr, bz, cex, dmg);
                // accumulate only if consumed at this sum's mid/final (k|3)
                if (D <= 7 - (k | 3)) {
                    kx += wk*tq.x; ky += wk*tq.y; kz += wk*tq.z;
                }

                if (kk < 3) {
                    twx = bmx + (F_H*tq.x)*cc;
                    twy = bmy + (F_H*tq.y)*cc;
                    twz = bmz + (F_H*tq.z)*cc;
                    tri[wsb][tid] = make_float4(twx, twy, twz, 0.f);
                } else {
                    // mid (k==3) / final (k==7): advance base by H/6 * ka
                    bmx += F_H6*kx; bmy += F_H6*ky; bmz += F_H6*kz;
                    kx = 0.f; ky = 0.f; kz = 0.f;
                    tri[0][tid] = make_float4(bmx, bmy, bmz, 0.f);
                    if (D == 0) {        // interior: publish at k==7, probes
                        const int tstep = 2*e + (k >> 2);
                        if (k == 7) {
                            union { unsigned long long u; float f[2]; } cv;
                            cv.f[0] = bmx; cv.f[1] = bmy;
                            st_coh_u64(&xy[(size_t)cb*NPLANE + gidx], cv.u);
                            st_coh_f32(&zz[(size_t)cb*NPLANE + gidx], bmz);
                        }
                        #pragma unroll
                        for (int j = 0; j < 4; ++j) {
                            if (gr == pr[j] && gc == pc[j]) {
                                out[tstep*4 + j] = bmz * ms;   // m0_z == 0
                            }
                        }
                    }
                }
            }
            __syncthreads();
        }

        // final barrier drained vmcnt: publish stores are at the coherence
        // point. Each writer thread posts into its partner's private slot.
        if (my_nb >= 0) {
            __hip_atomic_store(inbox + my_nb*FSTR + (7 - tid), e + 1,
                               __ATOMIC_RELAXED, __HIP_MEMORY_SCOPE_AGENT);
        }
    }
}

extern "C" void kernel_launch(void* const* d_in, const int* in_sizes, int n_in,
                              void* d_out, int out_size, void* d_ws, size_t ws_size,
                              hipStream_t stream) {
    const float* sig  = (const float*)d_in[0];
    const float* Bex  = (const float*)d_in[1];
    const float* Ms   = (const float*)d_in[2];
    const int*   srci = (const int*)d_in[3];
    const int*   prbi = (const int*)d_in[4];
    float* out = (float*)d_out;
    float* ws  = (float*)d_ws;

    void* args[] = { (void*)&sig, (void*)&Bex, (void*)&Ms,
                     (void*)&srci, (void*)&prbi, (void*)&out, (void*)&ws };
    hipLaunchCooperativeKernel((const void*)mm_persist, dim3(NBLK), dim3(NTHR),
                               args, 0, stream);
}